// Round 1
// baseline (1773.558 us; speedup 1.0000x reference)
//
#include <hip/hip_runtime.h>
#include <cstdint>
#include <cstddef>

// Problem constants (fixed by setup_inputs)
#define N_NODES 8192
#define E_RAW   131072
#define E_TOT   (E_RAW + N_NODES)   // 139264 (self-loops appended)
#define HEADS   4

// ---------------- helpers ----------------

__device__ __forceinline__ int eSrc(const int* __restrict__ src, int e) {
  return (e < E_RAW) ? src[e] : (e - E_RAW);
}
__device__ __forceinline__ int eDst(const int* __restrict__ dst, int e) {
  return (e < E_RAW) ? dst[e] : (e - E_RAW);
}

// atomic max on float (works for mixed signs; init with -inf)
__device__ __forceinline__ void atomicMaxF(float* addr, float v) {
  if (v >= 0.f) atomicMax((int*)addr, __float_as_int(v));
  else          atomicMin((unsigned int*)addr, __float_as_uint(v));
}

__global__ void fill_f(float* __restrict__ p, float v, int cnt) {
  int i = blockIdx.x * blockDim.x + threadIdx.x;
  if (i < cnt) p[i] = v;
}

// ---------------- build x = concat(c_temp, c_stereo, e_proj, f_Lt) ----------------

__global__ void build_x(const float* __restrict__ ct, const float* __restrict__ cs,
                        const float* __restrict__ ep, const float* __restrict__ fl,
                        float* __restrict__ x) {
  int i = blockIdx.x;  // node
  for (int j = threadIdx.x; j < 770; j += blockDim.x) {
    float v;
    if (j < 256)      v = ct[(size_t)i * 256 + j];
    else if (j < 512) v = cs[(size_t)i * 256 + (j - 256)];
    else if (j < 514) v = ep[(size_t)i * 2 + (j - 512)];
    else              v = fl[(size_t)i * 256 + (j - 514)];
    x[(size_t)i * 770 + j] = v;
  }
}

// ---------------- edge_attr mean (2-stage deterministic) ----------------

__global__ void ea_partial(const float* __restrict__ ea, float* __restrict__ part) {
  __shared__ float sm[256];
  int tid = threadIdx.x;
  float acc = 0.f;
  for (int i = blockIdx.x * 256 + tid; i < E_RAW; i += gridDim.x * 256) acc += ea[i];
  sm[tid] = acc; __syncthreads();
  for (int s = 128; s; s >>= 1) { if (tid < s) sm[tid] += sm[tid + s]; __syncthreads(); }
  if (tid == 0) part[blockIdx.x] = sm[0];
}

__global__ void ea_final(const float* __restrict__ part, float* __restrict__ mean) {
  __shared__ float sm[256];
  int tid = threadIdx.x;
  sm[tid] = part[tid]; __syncthreads();
  for (int s = 128; s; s >>= 1) { if (tid < s) sm[tid] += sm[tid + s]; __syncthreads(); }
  if (tid == 0) mean[0] = sm[0] * (1.f / (float)E_RAW);
}

// ---------------- generic fp32 GEMM: C = act(A[M,K] @ W[K,N] + bias) ----------------
// Requires M % 64 == 0, N % 64 == 0. K arbitrary.

#define BM 64
#define BN 64
#define BKK 16

template <int ACT>  // 0 none, 1 relu
__global__ __launch_bounds__(256) void gemm_kernel(
    const float* __restrict__ A, const float* __restrict__ W,
    const float* __restrict__ bias, float* __restrict__ C,
    int M, int N, int K) {
  __shared__ float As[BKK][BM + 1];
  __shared__ float Ws[BKK][BN + 1];
  int tid = threadIdx.x;
  int bm = blockIdx.y * BM;
  int bn = blockIdx.x * BN;
  int tx = tid & 15;
  int ty = tid >> 4;
  float acc[4][4] = {{0.f}};
  int ktiles = (K + BKK - 1) / BKK;
  for (int kt = 0; kt < ktiles; ++kt) {
    int k0 = kt * BKK;
#pragma unroll
    for (int i = 0; i < 4; ++i) {
      int lin = tid + i * 256;
      int r = lin >> 4, kk = lin & 15;
      int gk = k0 + kk;
      As[kk][r] = (gk < K) ? A[(size_t)(bm + r) * K + gk] : 0.f;
    }
#pragma unroll
    for (int i = 0; i < 4; ++i) {
      int lin = tid + i * 256;
      int kk = lin >> 6, nn = lin & 63;
      int gk = k0 + kk;
      Ws[kk][nn] = (gk < K) ? W[(size_t)gk * N + bn + nn] : 0.f;
    }
    __syncthreads();
#pragma unroll
    for (int kk = 0; kk < BKK; ++kk) {
      float a0[4], w0[4];
#pragma unroll
      for (int i = 0; i < 4; ++i) a0[i] = As[kk][ty * 4 + i];
#pragma unroll
      for (int j = 0; j < 4; ++j) w0[j] = Ws[kk][tx * 4 + j];
#pragma unroll
      for (int i = 0; i < 4; ++i)
#pragma unroll
        for (int j = 0; j < 4; ++j) acc[i][j] += a0[i] * w0[j];
    }
    __syncthreads();
  }
#pragma unroll
  for (int i = 0; i < 4; ++i) {
    int row = bm + ty * 4 + i;
#pragma unroll
    for (int j = 0; j < 4; ++j) {
      int col = bn + tx * 4 + j;
      float v = acc[i][j] + bias[col];
      if (ACT == 1) v = fmaxf(v, 0.f);
      C[(size_t)row * N + col] = v;
    }
  }
}

// ---------------- GATv2 edge scores + segment max ----------------
// one wave per (edge, head)

__global__ void gat_scores(const float* __restrict__ xl, const float* __restrict__ xr,
                           const int* __restrict__ src, const int* __restrict__ dst,
                           const float* __restrict__ ea, const float* __restrict__ eamean,
                           const float* __restrict__ We, const float* __restrict__ att,
                           float* __restrict__ sc, float* __restrict__ m,
                           int C) {
  int gw = (blockIdx.x * blockDim.x + threadIdx.x) >> 6;
  int lane = threadIdx.x & 63;
  int e = gw >> 2;            // H=4
  int hh = gw & 3;
  if (e >= E_TOT) return;
  int s = eSrc(src, e), d = eDst(dst, e);
  float eav = (e < E_RAW) ? ea[e] : eamean[0];
  int HC = HEADS * C;
  size_t sb = (size_t)s * HC + hh * C;
  size_t db = (size_t)d * HC + hh * C;
  float acc = 0.f;
  for (int c = lane; c < C; c += 64) {
    float v = xl[sb + c] + xr[db + c] + eav * We[hh * C + c];
    v = (v > 0.f) ? v : 0.2f * v;
    acc += v * att[hh * C + c];
  }
#pragma unroll
  for (int off = 32; off; off >>= 1) acc += __shfl_xor(acc, off, 64);
  if (lane == 0) {
    sc[(size_t)e * HEADS + hh] = acc;
    atomicMaxF(&m[(size_t)d * HEADS + hh], acc);
  }
}

// ---------------- exp + segment sum ----------------

__global__ void gat_expsum(float* __restrict__ sc, const float* __restrict__ m,
                           float* __restrict__ ssum, const int* __restrict__ dst) {
  int idx = blockIdx.x * blockDim.x + threadIdx.x;
  if (idx >= E_TOT * HEADS) return;
  int e = idx >> 2;
  int hh = idx & 3;
  int d = eDst(dst, e);
  float a = expf(sc[idx] - m[(size_t)d * HEADS + hh]);
  sc[idx] = a;
  atomicAdd(&ssum[(size_t)d * HEADS + hh], a);
}

// ---------------- scatter: out[dst] += alpha * xl[src] ----------------
// grid = E_TOT * bpe blocks of 256; H*C == bpe*256

__global__ void gat_scatter(const float* __restrict__ xl,
                            const int* __restrict__ src, const int* __restrict__ dst,
                            const float* __restrict__ aexp, const float* __restrict__ ssum,
                            float* __restrict__ out, int bpe, int C) {
  int b = blockIdx.x;
  int e = b / bpe;
  int j = (b - e * bpe) * 256 + threadIdx.x;
  int hh = j / C;
  int s = eSrc(src, e), d = eDst(dst, e);
  float alpha = aexp[(size_t)e * HEADS + hh] / (ssum[(size_t)d * HEADS + hh] + 1e-16f);
  int HC = HEADS * C;
  atomicAdd(&out[(size_t)d * HC + j], alpha * xl[(size_t)s * HC + j]);
}

// ---------------- conv1 epilogue: x1 = relu(acc + bias) ----------------

__global__ void add_bias_relu(const float* __restrict__ acc, const float* __restrict__ bias,
                              float* __restrict__ out) {
  size_t i = (size_t)blockIdx.x * 256 + threadIdx.x;  // total n*256
  int c = threadIdx.x;                                // blockDim == 256 == rowlen
  out[i] = fmaxf(acc[i] + bias[c], 0.f);
}

// ---------------- conv2 epilogue: x2 = mean over heads + bias ----------------

__global__ void head_mean_bias(const float* __restrict__ acc, const float* __restrict__ bias,
                               float* __restrict__ out) {
  int i = blockIdx.x;
  int c = threadIdx.x;
  size_t b = (size_t)i * 1024;
  float v = 0.25f * (acc[b + c] + acc[b + 256 + c] + acc[b + 512 + c] + acc[b + 768 + c]);
  out[(size_t)i * 256 + c] = v + bias[c];
}

// ---------------- GRU elementwise ----------------

__global__ void gru_kernel(const float* __restrict__ gi, const float* __restrict__ gh,
                           const float* __restrict__ hf, float* __restrict__ hn) {
  int i = blockIdx.x;
  int c = threadIdx.x;
  size_t b = (size_t)i * 768;
  float ir = gi[b + c], iz = gi[b + 256 + c], in_ = gi[b + 512 + c];
  float hr = gh[b + c], hz = gh[b + 256 + c], hn_ = gh[b + 512 + c];
  float r = 1.f / (1.f + expf(-(ir + hr)));
  float z = 1.f / (1.f + expf(-(iz + hz)));
  float ng = tanhf(in_ + r * hn_);
  float h0 = hf[(size_t)i * 256 + c];
  hn[(size_t)i * 256 + c] = (1.f - z) * ng + z * h0;
}

// ---------------- small final head GEMM (N<=2), wave per row ----------------

template <int ACT>  // 0 none, 1 sigmoid, 2 softplus
__global__ void head_small(const float* __restrict__ T, const float* __restrict__ W,
                           const float* __restrict__ b, float* __restrict__ out,
                           int K, int N) {
  int wid = (blockIdx.x * blockDim.x + threadIdx.x) >> 6;
  int lane = threadIdx.x & 63;
  if (wid >= N_NODES) return;
  for (int o = 0; o < N; ++o) {
    float acc = 0.f;
    for (int k = lane; k < K; k += 64) acc += T[(size_t)wid * K + k] * W[k * N + o];
#pragma unroll
    for (int off = 32; off; off >>= 1) acc += __shfl_xor(acc, off, 64);
    if (lane == 0) {
      float v = acc + b[o];
      if (ACT == 1) v = 1.f / (1.f + expf(-v));
      else if (ACT == 2) v = fmaxf(v, 0.f) + log1pf(expf(-fabsf(v)));
      out[(size_t)wid * N + o] = v;
    }
  }
}

// ---------------- a_p mean over N=2048 per batch ----------------

__global__ void ap_reduce(const float* __restrict__ ap, float* __restrict__ out) {
  __shared__ float sm[256];
  int b = blockIdx.x, tid = threadIdx.x;
  float acc = 0.f;
  for (int i = tid; i < 2048; i += 256) acc += ap[b * 2048 + i];
  sm[tid] = acc; __syncthreads();
  for (int s = 128; s; s >>= 1) { if (tid < s) sm[tid] += sm[tid + s]; __syncthreads(); }
  if (tid == 0) out[b] = sm[0] * (1.f / 2048.f);
}

// ---------------- launch ----------------

extern "C" void kernel_launch(void* const* d_in, const int* in_sizes, int n_in,
                              void* d_out, int out_size, void* d_ws, size_t ws_size,
                              hipStream_t stream) {
  // inputs
  const float* h        = (const float*)d_in[0];
  const float* c_temp   = (const float*)d_in[1];
  const float* c_stereo = (const float*)d_in[2];
  const float* e_proj   = (const float*)d_in[3];
  const float* f_Lt     = (const float*)d_in[4];
  const int*   edges    = (const int*)d_in[5];
  const float* eattr    = (const float*)d_in[6];
  const float* Wl1 = (const float*)d_in[7];  const float* bl1 = (const float*)d_in[8];
  const float* Wr1 = (const float*)d_in[9];  const float* br1 = (const float*)d_in[10];
  const float* We1 = (const float*)d_in[11]; const float* att1 = (const float*)d_in[12];
  const float* bias1 = (const float*)d_in[13];
  const float* Wl2 = (const float*)d_in[14]; const float* bl2 = (const float*)d_in[15];
  const float* Wr2 = (const float*)d_in[16]; const float* br2 = (const float*)d_in[17];
  const float* We2 = (const float*)d_in[18]; const float* att2 = (const float*)d_in[19];
  const float* bias2 = (const float*)d_in[20];
  const float* Wih = (const float*)d_in[21]; const float* bih = (const float*)d_in[22];
  const float* Whh = (const float*)d_in[23]; const float* bhh = (const float*)d_in[24];
  const float* rW1 = (const float*)d_in[25]; const float* rb1 = (const float*)d_in[26];
  const float* rW2 = (const float*)d_in[27]; const float* rb2 = (const float*)d_in[28];
  const float* wW1 = (const float*)d_in[29]; const float* wb1 = (const float*)d_in[30];
  const float* wW2 = (const float*)d_in[31]; const float* wb2 = (const float*)d_in[32];
  const float* pW1 = (const float*)d_in[33]; const float* pb1 = (const float*)d_in[34];
  const float* pW2 = (const float*)d_in[35]; const float* pb2 = (const float*)d_in[36];
  const float* dW1 = (const float*)d_in[37]; const float* db1 = (const float*)d_in[38];
  const float* dW2 = (const float*)d_in[39]; const float* db2 = (const float*)d_in[40];

  const int* src = edges;
  const int* dst = edges + E_RAW;

  // workspace layout (floats)
  const size_t R = 8388608;  // 8192*1024
  float* W0 = (float*)d_ws;          // x (6.3M) -> xl2 -> gi
  float* W1 = W0 + R;                // xl1+xr1 -> xr2 -> gh
  float* W2 = W1 + R;                // out1 -> out2 -> head temp T
  float* SC = W2 + R;                // edge scores / exp  (E_TOT*4)
  float* SM = SC + (size_t)E_TOT * 4;   // segment max (n*4)
  float* SS = SM + (size_t)N_NODES * 4; // segment sum (n*4)
  float* X1 = SS + (size_t)N_NODES * 4; // conv1 output (n*256)
  float* X2 = X1 + (size_t)N_NODES * 256; // conv2 output (n*256)
  float* AP = X2 + (size_t)N_NODES * 256; // per-node softplus for a_p (n)
  float* MP = AP + N_NODES;               // ea partials(256) + mean(1)

  size_t need_f = 3 * R + (size_t)E_TOT * 4 + (size_t)N_NODES * (4 + 4 + 256 + 256 + 1) + 257;
  if (ws_size < need_f * sizeof(float)) return;  // insufficient scratch -> visible failure

  float* xl1 = W1;
  float* xr1 = W1 + (size_t)N_NODES * 256;

  // outputs
  float* o_hnew = (float*)d_out;            // n*256
  float* o_res  = o_hnew + (size_t)N_NODES * 256;  // n*2
  float* o_w    = o_res + (size_t)N_NODES * 2;     // n*2
  float* o_ap   = o_w + (size_t)N_NODES * 2;       // 4
  float* o_ad   = o_ap + 4;                        // n*1

  // ---- stage 0: build x, edge_attr mean ----
  build_x<<<N_NODES, 256, 0, stream>>>(c_temp, c_stereo, e_proj, f_Lt, W0);
  ea_partial<<<256, 256, 0, stream>>>(eattr, MP);
  ea_final<<<1, 256, 0, stream>>>(MP, MP + 256);
  const float* eamean = MP + 256;

  // ---- conv1: xl1/xr1 ----
  gemm_kernel<0><<<dim3(256 / 64, N_NODES / 64), 256, 0, stream>>>(W0, Wl1, bl1, xl1, N_NODES, 256, 770);
  gemm_kernel<0><<<dim3(256 / 64, N_NODES / 64), 256, 0, stream>>>(W0, Wr1, br1, xr1, N_NODES, 256, 770);

  fill_f<<<(N_NODES * 4 + 255) / 256, 256, 0, stream>>>(SM, -INFINITY, N_NODES * 4);
  fill_f<<<(N_NODES * 4 + 255) / 256, 256, 0, stream>>>(SS, 0.f, N_NODES * 4);
  gat_scores<<<E_TOT, 256, 0, stream>>>(xl1, xr1, src, dst, eattr, eamean, We1, att1, SC, SM, 64);
  gat_expsum<<<(E_TOT * 4 + 255) / 256, 256, 0, stream>>>(SC, SM, SS, dst);
  fill_f<<<(N_NODES * 256 + 255) / 256, 256, 0, stream>>>(W2, 0.f, N_NODES * 256);
  gat_scatter<<<E_TOT, 256, 0, stream>>>(xl1, src, dst, SC, SS, W2, 1, 64);
  add_bias_relu<<<N_NODES * 256 / 256, 256, 0, stream>>>(W2, bias1, X1);

  // ---- conv2: xl2/xr2 ----
  gemm_kernel<0><<<dim3(1024 / 64, N_NODES / 64), 256, 0, stream>>>(X1, Wl2, bl2, W0, N_NODES, 1024, 256);
  gemm_kernel<0><<<dim3(1024 / 64, N_NODES / 64), 256, 0, stream>>>(X1, Wr2, br2, W1, N_NODES, 1024, 256);

  fill_f<<<(N_NODES * 4 + 255) / 256, 256, 0, stream>>>(SM, -INFINITY, N_NODES * 4);
  fill_f<<<(N_NODES * 4 + 255) / 256, 256, 0, stream>>>(SS, 0.f, N_NODES * 4);
  gat_scores<<<E_TOT, 256, 0, stream>>>(W0, W1, src, dst, eattr, eamean, We2, att2, SC, SM, 256);
  gat_expsum<<<(E_TOT * 4 + 255) / 256, 256, 0, stream>>>(SC, SM, SS, dst);
  fill_f<<<(N_NODES * 1024 + 255) / 256, 256, 0, stream>>>(W2, 0.f, N_NODES * 1024);
  gat_scatter<<<E_TOT * 4, 256, 0, stream>>>(W0, src, dst, SC, SS, W2, 4, 256);
  head_mean_bias<<<N_NODES, 256, 0, stream>>>(W2, bias2, X2);

  // ---- GRU ----
  gemm_kernel<0><<<dim3(768 / 64, N_NODES / 64), 256, 0, stream>>>(X2, Wih, bih, W0, N_NODES, 768, 256);
  gemm_kernel<0><<<dim3(768 / 64, N_NODES / 64), 256, 0, stream>>>(h, Whh, bhh, W1, N_NODES, 768, 256);
  gru_kernel<<<N_NODES, 256, 0, stream>>>(W0, W1, h, o_hnew);

  // ---- heads ----
  // res
  gemm_kernel<1><<<dim3(256 / 64, N_NODES / 64), 256, 0, stream>>>(o_hnew, rW1, rb1, W2, N_NODES, 256, 256);
  head_small<0><<<N_NODES / 4, 256, 0, stream>>>(W2, rW2, rb2, o_res, 256, 2);
  // w
  gemm_kernel<1><<<dim3(256 / 64, N_NODES / 64), 256, 0, stream>>>(o_hnew, wW1, wb1, W2, N_NODES, 256, 256);
  head_small<1><<<N_NODES / 4, 256, 0, stream>>>(W2, wW2, wb2, o_w, 256, 2);
  // a_p
  gemm_kernel<1><<<dim3(128 / 64, N_NODES / 64), 256, 0, stream>>>(o_hnew, pW1, pb1, W2, N_NODES, 128, 256);
  head_small<2><<<N_NODES / 4, 256, 0, stream>>>(W2, pW2, pb2, AP, 128, 1);
  ap_reduce<<<4, 256, 0, stream>>>(AP, o_ap);
  // a_d
  gemm_kernel<1><<<dim3(128 / 64, N_NODES / 64), 256, 0, stream>>>(o_hnew, dW1, db1, W2, N_NODES, 128, 256);
  head_small<2><<<N_NODES / 4, 256, 0, stream>>>(W2, dW2, db2, o_ad, 128, 1);
}

// Round 2
// 1282.214 us; speedup vs baseline: 1.3832x; 1.3832x over previous
//
#include <hip/hip_runtime.h>
#include <cstdint>
#include <cstddef>

// Problem constants (fixed by setup_inputs)
#define N_NODES 8192
#define E_RAW   131072
#define E_TOT   (E_RAW + N_NODES)   // 139264 (self-loops appended)
#define HEADS   4

// ---------------- helpers ----------------

__device__ __forceinline__ int eSrc(const int* __restrict__ src, int e) {
  return (e < E_RAW) ? src[e] : (e - E_RAW);
}
__device__ __forceinline__ int eDst(const int* __restrict__ dst, int e) {
  return (e < E_RAW) ? dst[e] : (e - E_RAW);
}

__global__ void fill_i(int* __restrict__ p, int v, int cnt) {
  int i = blockIdx.x * blockDim.x + threadIdx.x;
  if (i < cnt) p[i] = v;
}

// ---------------- build x = concat(c_temp, c_stereo, e_proj, f_Lt) ----------------

__global__ void build_x(const float* __restrict__ ct, const float* __restrict__ cs,
                        const float* __restrict__ ep, const float* __restrict__ fl,
                        float* __restrict__ x) {
  int i = blockIdx.x;  // node
  for (int j = threadIdx.x; j < 770; j += blockDim.x) {
    float v;
    if (j < 256)      v = ct[(size_t)i * 256 + j];
    else if (j < 512) v = cs[(size_t)i * 256 + (j - 256)];
    else if (j < 514) v = ep[(size_t)i * 2 + (j - 512)];
    else              v = fl[(size_t)i * 256 + (j - 514)];
    x[(size_t)i * 770 + j] = v;
  }
}

// ---------------- edge_attr mean (2-stage deterministic) ----------------

__global__ void ea_partial(const float* __restrict__ ea, float* __restrict__ part) {
  __shared__ float sm[256];
  int tid = threadIdx.x;
  float acc = 0.f;
  for (int i = blockIdx.x * 256 + tid; i < E_RAW; i += gridDim.x * 256) acc += ea[i];
  sm[tid] = acc; __syncthreads();
  for (int s = 128; s; s >>= 1) { if (tid < s) sm[tid] += sm[tid + s]; __syncthreads(); }
  if (tid == 0) part[blockIdx.x] = sm[0];
}

__global__ void ea_final(const float* __restrict__ part, float* __restrict__ mean) {
  __shared__ float sm[256];
  int tid = threadIdx.x;
  sm[tid] = part[tid]; __syncthreads();
  for (int s = 128; s; s >>= 1) { if (tid < s) sm[tid] += sm[tid + s]; __syncthreads(); }
  if (tid == 0) mean[0] = sm[0] * (1.f / (float)E_RAW);
}

// ---------------- CSR build (sort edges by dst) ----------------

__global__ void csr_count(const int* __restrict__ dst, int* __restrict__ cnt) {
  int e = blockIdx.x * blockDim.x + threadIdx.x;
  if (e < E_TOT) atomicAdd(&cnt[eDst(dst, e)], 1);
}

// one block of 1024 threads; 8 entries per thread; exclusive scan of 8192
__global__ __launch_bounds__(1024) void csr_scan(const int* __restrict__ cnt,
                                                 int* __restrict__ off) {
  __shared__ int part[1024];
  int t = threadIdx.x;
  int base = t * 8;
  int loc[8];
  int s = 0;
#pragma unroll
  for (int i = 0; i < 8; ++i) { loc[i] = s; s += cnt[base + i]; }
  part[t] = s; __syncthreads();
  for (int d = 1; d < 1024; d <<= 1) {
    int v = (t >= d) ? part[t - d] : 0;
    __syncthreads();
    part[t] += v;
    __syncthreads();
  }
  int pre = (t == 0) ? 0 : part[t - 1];
#pragma unroll
  for (int i = 0; i < 8; ++i) off[base + i] = pre + loc[i];
  if (t == 1023) off[8192] = part[1023];
}

__global__ void csr_fill(const int* __restrict__ src, const int* __restrict__ dst,
                         const int* __restrict__ off, int* __restrict__ pos,
                         int* __restrict__ eid, int* __restrict__ srcn) {
  int e = blockIdx.x * blockDim.x + threadIdx.x;
  if (e >= E_TOT) return;
  int d = eDst(dst, e);
  int p = off[d] + atomicAdd(&pos[d], 1);
  eid[p] = e;
  srcn[p] = eSrc(src, e);
}

// ---------------- generic fp32 GEMM: C = act(A[M,K] @ W[K,N] + bias) ----------------

#define BM 64
#define BN 64
#define BKK 16

template <int ACT>  // 0 none, 1 relu
__global__ __launch_bounds__(256) void gemm_kernel(
    const float* __restrict__ A, const float* __restrict__ W,
    const float* __restrict__ bias, float* __restrict__ C,
    int M, int N, int K) {
  __shared__ float As[BKK][BM + 1];
  __shared__ float Ws[BKK][BN + 1];
  int tid = threadIdx.x;
  int bm = blockIdx.y * BM;
  int bn = blockIdx.x * BN;
  int tx = tid & 15;
  int ty = tid >> 4;
  float acc[4][4] = {{0.f}};
  int ktiles = (K + BKK - 1) / BKK;
  for (int kt = 0; kt < ktiles; ++kt) {
    int k0 = kt * BKK;
#pragma unroll
    for (int i = 0; i < 4; ++i) {
      int lin = tid + i * 256;
      int r = lin >> 4, kk = lin & 15;
      int gk = k0 + kk;
      As[kk][r] = (gk < K) ? A[(size_t)(bm + r) * K + gk] : 0.f;
    }
#pragma unroll
    for (int i = 0; i < 4; ++i) {
      int lin = tid + i * 256;
      int kk = lin >> 6, nn = lin & 63;
      int gk = k0 + kk;
      Ws[kk][nn] = (gk < K) ? W[(size_t)gk * N + bn + nn] : 0.f;
    }
    __syncthreads();
#pragma unroll
    for (int kk = 0; kk < BKK; ++kk) {
      float a0[4], w0[4];
#pragma unroll
      for (int i = 0; i < 4; ++i) a0[i] = As[kk][ty * 4 + i];
#pragma unroll
      for (int j = 0; j < 4; ++j) w0[j] = Ws[kk][tx * 4 + j];
#pragma unroll
      for (int i = 0; i < 4; ++i)
#pragma unroll
        for (int j = 0; j < 4; ++j) acc[i][j] += a0[i] * w0[j];
    }
    __syncthreads();
  }
#pragma unroll
  for (int i = 0; i < 4; ++i) {
    int row = bm + ty * 4 + i;
#pragma unroll
    for (int j = 0; j < 4; ++j) {
      int col = bn + tx * 4 + j;
      float v = acc[i][j] + bias[col];
      if (ACT == 1) v = fmaxf(v, 0.f);
      C[(size_t)row * N + col] = v;
    }
  }
}

// ---------------- GATv2 edge scores (no atomics) ----------------
// one wave per (edge, head)

__global__ void gat_scores(const float* __restrict__ xl, const float* __restrict__ xr,
                           const int* __restrict__ src, const int* __restrict__ dst,
                           const float* __restrict__ ea, const float* __restrict__ eamean,
                           const float* __restrict__ We, const float* __restrict__ att,
                           float* __restrict__ sc, int C) {
  int gw = (blockIdx.x * blockDim.x + threadIdx.x) >> 6;
  int lane = threadIdx.x & 63;
  int e = gw >> 2;            // H=4
  int hh = gw & 3;
  if (e >= E_TOT) return;
  int s = eSrc(src, e), d = eDst(dst, e);
  float eav = (e < E_RAW) ? ea[e] : eamean[0];
  int HC = HEADS * C;
  size_t sb = (size_t)s * HC + hh * C;
  size_t db = (size_t)d * HC + hh * C;
  float acc = 0.f;
  for (int c = lane; c < C; c += 64) {
    float v = xl[sb + c] + xr[db + c] + eav * We[hh * C + c];
    v = (v > 0.f) ? v : 0.2f * v;
    acc += v * att[hh * C + c];
  }
#pragma unroll
  for (int off = 32; off; off >>= 1) acc += __shfl_xor(acc, off, 64);
  if (lane == 0) sc[(size_t)e * HEADS + hh] = acc;
}

// ---------------- per-node softmax over incoming edges ----------------
// one block (4 waves) per node; wave hh handles head hh; writes alpha in CSR order

__global__ void gat_softmax(const float* __restrict__ sc, const int* __restrict__ off,
                            const int* __restrict__ eid, float* __restrict__ al) {
  int d = blockIdx.x;
  int hh = threadIdx.x >> 6;
  int lane = threadIdx.x & 63;
  int b = off[d];
  int deg = off[d + 1] - b;
  float m = -INFINITY;
  for (int k = lane; k < deg; k += 64) m = fmaxf(m, sc[(size_t)eid[b + k] * 4 + hh]);
#pragma unroll
  for (int o = 32; o; o >>= 1) m = fmaxf(m, __shfl_xor(m, o, 64));
  float s = 0.f;
  for (int k = lane; k < deg; k += 64) s += expf(sc[(size_t)eid[b + k] * 4 + hh] - m);
#pragma unroll
  for (int o = 32; o; o >>= 1) s += __shfl_xor(s, o, 64);
  float inv = 1.f / (s + 1e-16f);
  for (int k = lane; k < deg; k += 64)
    al[(size_t)(b + k) * 4 + hh] = expf(sc[(size_t)eid[b + k] * 4 + hh] - m) * inv;
}

// ---------------- conv1 aggregation (gather) + bias + relu ----------------
// block per node, 256 threads; HC=256, C=64 (head = j>>6)

__global__ __launch_bounds__(256) void gat_agg1(
    const float* __restrict__ xl, const int* __restrict__ off,
    const int* __restrict__ srcn, const float* __restrict__ al,
    const float* __restrict__ bias, float* __restrict__ out) {
  int d = blockIdx.x;
  int j = threadIdx.x;
  int hh = j >> 6;
  int b = off[d];
  int deg = off[d + 1] - b;
  float acc = 0.f;
  for (int k = 0; k < deg; ++k) {
    int p = b + k;
    acc += al[(size_t)p * 4 + hh] * xl[(size_t)srcn[p] * 256 + j];
  }
  out[(size_t)d * 256 + j] = fmaxf(acc + bias[j], 0.f);
}

// ---------------- conv2 aggregation (gather) + head-mean + bias ----------------
// block per node, 256 threads; HC=1024, C=256; fuses mean over 4 heads

__global__ __launch_bounds__(256) void gat_agg2(
    const float* __restrict__ xl, const int* __restrict__ off,
    const int* __restrict__ srcn, const float* __restrict__ al,
    const float* __restrict__ bias, float* __restrict__ out) {
  int d = blockIdx.x;
  int j = threadIdx.x;
  int b = off[d];
  int deg = off[d + 1] - b;
  float a0 = 0.f, a1 = 0.f, a2 = 0.f, a3 = 0.f;
  for (int k = 0; k < deg; ++k) {
    int p = b + k;
    size_t rb = (size_t)srcn[p] * 1024 + j;
    const float* alp = &al[(size_t)p * 4];
    a0 += alp[0] * xl[rb];
    a1 += alp[1] * xl[rb + 256];
    a2 += alp[2] * xl[rb + 512];
    a3 += alp[3] * xl[rb + 768];
  }
  out[(size_t)d * 256 + j] = 0.25f * (a0 + a1 + a2 + a3) + bias[j];
}

// ---------------- GRU elementwise ----------------

__global__ void gru_kernel(const float* __restrict__ gi, const float* __restrict__ gh,
                           const float* __restrict__ hf, float* __restrict__ hn) {
  int i = blockIdx.x;
  int c = threadIdx.x;
  size_t b = (size_t)i * 768;
  float ir = gi[b + c], iz = gi[b + 256 + c], in_ = gi[b + 512 + c];
  float hr = gh[b + c], hz = gh[b + 256 + c], hn_ = gh[b + 512 + c];
  float r = 1.f / (1.f + expf(-(ir + hr)));
  float z = 1.f / (1.f + expf(-(iz + hz)));
  float ng = tanhf(in_ + r * hn_);
  float h0 = hf[(size_t)i * 256 + c];
  hn[(size_t)i * 256 + c] = (1.f - z) * ng + z * h0;
}

// ---------------- small final head GEMM (N<=2), wave per row ----------------

template <int ACT>  // 0 none, 1 sigmoid, 2 softplus
__global__ void head_small(const float* __restrict__ T, const float* __restrict__ W,
                           const float* __restrict__ b, float* __restrict__ out,
                           int K, int N) {
  int wid = (blockIdx.x * blockDim.x + threadIdx.x) >> 6;
  int lane = threadIdx.x & 63;
  if (wid >= N_NODES) return;
  for (int o = 0; o < N; ++o) {
    float acc = 0.f;
    for (int k = lane; k < K; k += 64) acc += T[(size_t)wid * K + k] * W[k * N + o];
#pragma unroll
    for (int off = 32; off; off >>= 1) acc += __shfl_xor(acc, off, 64);
    if (lane == 0) {
      float v = acc + b[o];
      if (ACT == 1) v = 1.f / (1.f + expf(-v));
      else if (ACT == 2) v = fmaxf(v, 0.f) + log1pf(expf(-fabsf(v)));
      out[(size_t)wid * N + o] = v;
    }
  }
}

// ---------------- a_p mean over N=2048 per batch ----------------

__global__ void ap_reduce(const float* __restrict__ ap, float* __restrict__ out) {
  __shared__ float sm[256];
  int b = blockIdx.x, tid = threadIdx.x;
  float acc = 0.f;
  for (int i = tid; i < 2048; i += 256) acc += ap[b * 2048 + i];
  sm[tid] = acc; __syncthreads();
  for (int s = 128; s; s >>= 1) { if (tid < s) sm[tid] += sm[tid + s]; __syncthreads(); }
  if (tid == 0) out[b] = sm[0] * (1.f / 2048.f);
}

// ---------------- launch ----------------

extern "C" void kernel_launch(void* const* d_in, const int* in_sizes, int n_in,
                              void* d_out, int out_size, void* d_ws, size_t ws_size,
                              hipStream_t stream) {
  // inputs
  const float* h        = (const float*)d_in[0];
  const float* c_temp   = (const float*)d_in[1];
  const float* c_stereo = (const float*)d_in[2];
  const float* e_proj   = (const float*)d_in[3];
  const float* f_Lt     = (const float*)d_in[4];
  const int*   edges    = (const int*)d_in[5];
  const float* eattr    = (const float*)d_in[6];
  const float* Wl1 = (const float*)d_in[7];  const float* bl1 = (const float*)d_in[8];
  const float* Wr1 = (const float*)d_in[9];  const float* br1 = (const float*)d_in[10];
  const float* We1 = (const float*)d_in[11]; const float* att1 = (const float*)d_in[12];
  const float* bias1 = (const float*)d_in[13];
  const float* Wl2 = (const float*)d_in[14]; const float* bl2 = (const float*)d_in[15];
  const float* Wr2 = (const float*)d_in[16]; const float* br2 = (const float*)d_in[17];
  const float* We2 = (const float*)d_in[18]; const float* att2 = (const float*)d_in[19];
  const float* bias2 = (const float*)d_in[20];
  const float* Wih = (const float*)d_in[21]; const float* bih = (const float*)d_in[22];
  const float* Whh = (const float*)d_in[23]; const float* bhh = (const float*)d_in[24];
  const float* rW1 = (const float*)d_in[25]; const float* rb1 = (const float*)d_in[26];
  const float* rW2 = (const float*)d_in[27]; const float* rb2 = (const float*)d_in[28];
  const float* wW1 = (const float*)d_in[29]; const float* wb1 = (const float*)d_in[30];
  const float* wW2 = (const float*)d_in[31]; const float* wb2 = (const float*)d_in[32];
  const float* pW1 = (const float*)d_in[33]; const float* pb1 = (const float*)d_in[34];
  const float* pW2 = (const float*)d_in[35]; const float* pb2 = (const float*)d_in[36];
  const float* dW1 = (const float*)d_in[37]; const float* db1 = (const float*)d_in[38];
  const float* dW2 = (const float*)d_in[39]; const float* db2 = (const float*)d_in[40];

  const int* src = edges;
  const int* dst = edges + E_RAW;

  // workspace layout (floats)
  const size_t R = 8388608;  // 8192*1024
  float* W0 = (float*)d_ws;               // x (6.3M) -> xl2 (8.39M) -> gi (6.3M)
  float* W1 = W0 + R;                     // xl1+xr1 (4.2M) -> xr2 (8.39M) -> gh
  float* W2 = W1 + R;                     // head temp T (n*256)
  float* SC = W2 + (size_t)N_NODES * 256; // edge scores (E_TOT*4)
  float* AL = SC + (size_t)E_TOT * 4;     // alphas in CSR order (E_TOT*4)
  float* X1 = AL + (size_t)E_TOT * 4;     // conv1 output (n*256)
  float* X2 = X1 + (size_t)N_NODES * 256; // conv2 output (n*256)
  float* AP = X2 + (size_t)N_NODES * 256; // per-node softplus for a_p (n)
  float* MP = AP + N_NODES;               // ea partials(256) + mean(1)
  // int scratch after MP
  int* ICNT = (int*)(MP + 257);           // 8192
  int* IOFF = ICNT + N_NODES;             // 8193
  int* IPOS = IOFF + (N_NODES + 1);       // 8192
  int* IEID = IPOS + N_NODES;             // E_TOT
  int* ISRC = IEID + E_TOT;               // E_TOT

  size_t need_w = 2 * R + (size_t)N_NODES * 256        // W0,W1,W2
                + (size_t)E_TOT * 8                     // SC, AL
                + (size_t)N_NODES * (256 + 256 + 1) + 257
                + (3 * (size_t)N_NODES + 1 + 2 * (size_t)E_TOT);  // ints (1 word each)
  if (ws_size < need_w * 4) return;  // insufficient scratch -> visible failure

  float* xl1 = W1;
  float* xr1 = W1 + (size_t)N_NODES * 256;

  // outputs
  float* o_hnew = (float*)d_out;                   // n*256
  float* o_res  = o_hnew + (size_t)N_NODES * 256;  // n*2
  float* o_w    = o_res + (size_t)N_NODES * 2;     // n*2
  float* o_ap   = o_w + (size_t)N_NODES * 2;       // 4
  float* o_ad   = o_ap + 4;                        // n*1

  // ---- stage 0: build x, edge_attr mean, CSR ----
  build_x<<<N_NODES, 256, 0, stream>>>(c_temp, c_stereo, e_proj, f_Lt, W0);
  ea_partial<<<256, 256, 0, stream>>>(eattr, MP);
  ea_final<<<1, 256, 0, stream>>>(MP, MP + 256);
  const float* eamean = MP + 256;

  fill_i<<<(2 * N_NODES + 255) / 256, 256, 0, stream>>>(ICNT, 0, N_NODES);
  fill_i<<<(N_NODES + 255) / 256, 256, 0, stream>>>(IPOS, 0, N_NODES);
  csr_count<<<(E_TOT + 255) / 256, 256, 0, stream>>>(dst, ICNT);
  csr_scan<<<1, 1024, 0, stream>>>(ICNT, IOFF);
  csr_fill<<<(E_TOT + 255) / 256, 256, 0, stream>>>(src, dst, IOFF, IPOS, IEID, ISRC);

  // ---- conv1 ----
  gemm_kernel<0><<<dim3(256 / 64, N_NODES / 64), 256, 0, stream>>>(W0, Wl1, bl1, xl1, N_NODES, 256, 770);
  gemm_kernel<0><<<dim3(256 / 64, N_NODES / 64), 256, 0, stream>>>(W0, Wr1, br1, xr1, N_NODES, 256, 770);
  gat_scores<<<E_TOT, 256, 0, stream>>>(xl1, xr1, src, dst, eattr, eamean, We1, att1, SC, 64);
  gat_softmax<<<N_NODES, 256, 0, stream>>>(SC, IOFF, IEID, AL);
  gat_agg1<<<N_NODES, 256, 0, stream>>>(xl1, IOFF, ISRC, AL, bias1, X1);

  // ---- conv2 ----
  gemm_kernel<0><<<dim3(1024 / 64, N_NODES / 64), 256, 0, stream>>>(X1, Wl2, bl2, W0, N_NODES, 1024, 256);
  gemm_kernel<0><<<dim3(1024 / 64, N_NODES / 64), 256, 0, stream>>>(X1, Wr2, br2, W1, N_NODES, 1024, 256);
  gat_scores<<<E_TOT, 256, 0, stream>>>(W0, W1, src, dst, eattr, eamean, We2, att2, SC, 256);
  gat_softmax<<<N_NODES, 256, 0, stream>>>(SC, IOFF, IEID, AL);
  gat_agg2<<<N_NODES, 256, 0, stream>>>(W0, IOFF, ISRC, AL, bias2, X2);

  // ---- GRU ----
  gemm_kernel<0><<<dim3(768 / 64, N_NODES / 64), 256, 0, stream>>>(X2, Wih, bih, W0, N_NODES, 768, 256);
  gemm_kernel<0><<<dim3(768 / 64, N_NODES / 64), 256, 0, stream>>>(h, Whh, bhh, W1, N_NODES, 768, 256);
  gru_kernel<<<N_NODES, 256, 0, stream>>>(W0, W1, h, o_hnew);

  // ---- heads ----
  gemm_kernel<1><<<dim3(256 / 64, N_NODES / 64), 256, 0, stream>>>(o_hnew, rW1, rb1, W2, N_NODES, 256, 256);
  head_small<0><<<N_NODES / 4, 256, 0, stream>>>(W2, rW2, rb2, o_res, 256, 2);
  gemm_kernel<1><<<dim3(256 / 64, N_NODES / 64), 256, 0, stream>>>(o_hnew, wW1, wb1, W2, N_NODES, 256, 256);
  head_small<1><<<N_NODES / 4, 256, 0, stream>>>(W2, wW2, wb2, o_w, 256, 2);
  gemm_kernel<1><<<dim3(128 / 64, N_NODES / 64), 256, 0, stream>>>(o_hnew, pW1, pb1, W2, N_NODES, 128, 256);
  head_small<2><<<N_NODES / 4, 256, 0, stream>>>(W2, pW2, pb2, AP, 128, 1);
  ap_reduce<<<4, 256, 0, stream>>>(AP, o_ap);
  gemm_kernel<1><<<dim3(128 / 64, N_NODES / 64), 256, 0, stream>>>(o_hnew, dW1, db1, W2, N_NODES, 128, 256);
  head_small<2><<<N_NODES / 4, 256, 0, stream>>>(W2, dW2, db2, o_ad, 128, 1);
}

// Round 3
// 307.413 us; speedup vs baseline: 5.7693x; 4.1710x over previous
//
#include <hip/hip_runtime.h>
#include <hip/hip_bf16.h>
#include <cstdint>
#include <cstddef>

#define N_NODES 8192
#define E_RAW   131072
#define E_TOT   (E_RAW + N_NODES)   // 139264
#define HEADS   4

typedef __attribute__((ext_vector_type(8))) __bf16 bf16x8;
typedef __attribute__((ext_vector_type(4))) float f32x4;

__device__ __forceinline__ void gload_lds16(const void* g, void* lds) {
  __builtin_amdgcn_global_load_lds(
      (const __attribute__((address_space(1))) unsigned int*)g,
      (__attribute__((address_space(3))) unsigned int*)lds, 16, 0, 0);
}

__device__ __forceinline__ float bfbits2f(unsigned short u) {
  return __uint_as_float((unsigned)u << 16);
}

__device__ __forceinline__ int eSrc(const int* __restrict__ src, int e) {
  return (e < E_RAW) ? src[e] : (e - E_RAW);
}
__device__ __forceinline__ int eDst(const int* __restrict__ dst, int e) {
  return (e < E_RAW) ? dst[e] : (e - E_RAW);
}

__global__ void fill_i(int* __restrict__ p, int v, int cnt) {
  int i = blockIdx.x * blockDim.x + threadIdx.x;
  if (i < cnt) p[i] = v;
}

// ---------------- build x (bf16, K padded 770->832) ----------------

__global__ void build_x_bf(const float* __restrict__ ct, const float* __restrict__ cs,
                           const float* __restrict__ ep, const float* __restrict__ fl,
                           __hip_bfloat16* __restrict__ x) {
  int i = blockIdx.x;
  for (int j = threadIdx.x; j < 832; j += 256) {
    float v;
    if (j < 256)      v = ct[(size_t)i * 256 + j];
    else if (j < 512) v = cs[(size_t)i * 256 + (j - 256)];
    else if (j < 514) v = ep[(size_t)i * 2 + (j - 512)];
    else if (j < 770) v = fl[(size_t)i * 256 + (j - 514)];
    else              v = 0.f;
    x[(size_t)i * 832 + j] = __float2bfloat16(v);
  }
}

// ---------------- edge_attr mean ----------------

__global__ void ea_partial(const float* __restrict__ ea, float* __restrict__ part) {
  __shared__ float sm[256];
  int tid = threadIdx.x;
  float acc = 0.f;
  for (int i = blockIdx.x * 256 + tid; i < E_RAW; i += gridDim.x * 256) acc += ea[i];
  sm[tid] = acc; __syncthreads();
  for (int s = 128; s; s >>= 1) { if (tid < s) sm[tid] += sm[tid + s]; __syncthreads(); }
  if (tid == 0) part[blockIdx.x] = sm[0];
}

__global__ void ea_final(const float* __restrict__ part, float* __restrict__ mean) {
  __shared__ float sm[256];
  int tid = threadIdx.x;
  sm[tid] = part[tid]; __syncthreads();
  for (int s = 128; s; s >>= 1) { if (tid < s) sm[tid] += sm[tid + s]; __syncthreads(); }
  if (tid == 0) mean[0] = sm[0] * (1.f / (float)E_RAW);
}

// ---------------- CSR build ----------------

__global__ void csr_count(const int* __restrict__ dst, int* __restrict__ cnt) {
  int e = blockIdx.x * blockDim.x + threadIdx.x;
  if (e < E_TOT) atomicAdd(&cnt[eDst(dst, e)], 1);
}

__global__ __launch_bounds__(1024) void csr_scan(const int* __restrict__ cnt,
                                                 int* __restrict__ off) {
  __shared__ int part[1024];
  int t = threadIdx.x;
  int base = t * 8;
  int loc[8];
  int s = 0;
#pragma unroll
  for (int i = 0; i < 8; ++i) { loc[i] = s; s += cnt[base + i]; }
  part[t] = s; __syncthreads();
  for (int d = 1; d < 1024; d <<= 1) {
    int v = (t >= d) ? part[t - d] : 0;
    __syncthreads();
    part[t] += v;
    __syncthreads();
  }
  int pre = (t == 0) ? 0 : part[t - 1];
#pragma unroll
  for (int i = 0; i < 8; ++i) off[base + i] = pre + loc[i];
  if (t == 1023) off[8192] = part[1023];
}

__global__ void csr_fill(const int* __restrict__ src, const int* __restrict__ dst,
                         const float* __restrict__ ea, const float* __restrict__ eamean,
                         const int* __restrict__ off, int* __restrict__ pos,
                         int* __restrict__ srcn, float* __restrict__ eav) {
  int e = blockIdx.x * blockDim.x + threadIdx.x;
  if (e >= E_TOT) return;
  int d = eDst(dst, e);
  int p = off[d] + atomicAdd(&pos[d], 1);
  srcn[p] = eSrc(src, e);
  eav[p] = (e < E_RAW) ? ea[e] : eamean[0];
}

// ---------------- weight transpose + bf16 convert: W[K][N] -> WT[n0+n][k] (row KP) ----------------

__global__ void wt_conv(const float* __restrict__ W, __hip_bfloat16* __restrict__ WT,
                        int K, int N, int KP, int n0) {
  __shared__ float sm[32][33];
  int k0 = blockIdx.x * 32, nb = blockIdx.y * 32;
  int tx = threadIdx.x & 31, ty = threadIdx.x >> 5;  // 256 threads
  for (int yy = ty; yy < 32; yy += 8) {
    int k = k0 + yy, n = nb + tx;
    sm[yy][tx] = (k < K && n < N) ? W[(size_t)k * N + n] : 0.f;
  }
  __syncthreads();
  for (int yy = ty; yy < 32; yy += 8) {
    int n = nb + yy, k = k0 + tx;
    if (n < N && k < KP)
      WT[(size_t)(n0 + n) * KP + k] = __float2bfloat16(sm[tx][yy]);
  }
}

__global__ void cvt_bf(const float* __restrict__ s, __hip_bfloat16* __restrict__ d, int n) {
  int i = blockIdx.x * 256 + threadIdx.x;
  if (i < n) d[i] = __float2bfloat16(s[i]);
}

__global__ void build_biases(const float* bl1, const float* br1,
                             const float* bl2, const float* br2,
                             const float* rb1, const float* wb1,
                             const float* pb1, const float* db1,
                             float* B1, float* B2, float* BH) {
  int i = blockIdx.x * 256 + threadIdx.x;
  if (i < 512) B1[i] = (i < 256) ? bl1[i] : br1[i - 256];
  else if (i < 2560) { int k = i - 512; B2[k] = (k < 1024) ? bl2[k] : br2[k - 1024]; }
  else if (i < 3328) {
    int k = i - 2560;
    BH[k] = (k < 256) ? rb1[k] : (k < 512) ? wb1[k - 256] : (k < 640) ? pb1[k - 512] : db1[k - 640];
  }
}

// ---------------- bf16 MFMA GEMM: C = act(A[M,KP] @ WT^T + bias) ----------------
// A: bf16 [M][KP] row-major; WT: bf16 [N][KP] row-major (i.e., W^T).
// Tile 128x128, BK=64, 4 waves, 16x16x32 MFMA, XOR-swizzled LDS (chunk ^= row&7).
// Requires M%128==0, N%128==0, KP%64==0.

template <int OUT>  // 0: bf16 store, 1: f32 store, 2: f32 relu store
__global__ __launch_bounds__(256) void mfma_gemm(
    const __hip_bfloat16* __restrict__ A, const __hip_bfloat16* __restrict__ BT,
    const float* __restrict__ bias, void* __restrict__ Cout, int KP, int N,
    const __hip_bfloat16* A2, const __hip_bfloat16* BT2,
    const float* bias2, void* C2) {
  if (blockIdx.z == 1) { A = A2; BT = BT2; bias = bias2; Cout = C2; }
  __shared__ uint4 AsBuf[1024];   // 16KB: [128 rows][64 k] bf16
  __shared__ uint4 BsBuf[1024];   // 16KB: [128 n]  [64 k] bf16
  char* Asc = (char*)AsBuf;
  char* Bsc = (char*)BsBuf;
  int tid = threadIdx.x;
  int lane = tid & 63;
  int wid = tid >> 6;
  int wr = wid >> 1, wc = wid & 1;
  int bm = blockIdx.y * 128;
  int bn = blockIdx.x * 128;
  f32x4 acc[4][4];
#pragma unroll
  for (int i = 0; i < 4; ++i)
#pragma unroll
    for (int j = 0; j < 4; ++j) acc[i][j] = (f32x4){0.f, 0.f, 0.f, 0.f};

  int nK = KP >> 6;
  for (int kt = 0; kt < nK; ++kt) {
    int k0 = kt * 64;
#pragma unroll
    for (int i = 0; i < 4; ++i) {
      int p = i * 256 + tid;          // 16B chunk index, 0..1023
      int row = p >> 3, cc = p & 7;
      int sc = cc ^ (row & 7);        // inverse-swizzled global source
      gload_lds16(A + (size_t)(bm + row) * KP + k0 + sc * 8, Asc + p * 16);
      gload_lds16(BT + (size_t)(bn + row) * KP + k0 + sc * 8, Bsc + p * 16);
    }
    __syncthreads();
#pragma unroll
    for (int s = 0; s < 2; ++s) {
      bf16x8 af[4], bfr[4];
#pragma unroll
      for (int f = 0; f < 4; ++f) {
        int r = wr * 64 + f * 16 + (lane & 15);
        int ch = (s * 4 + (lane >> 4)) ^ (r & 7);
        af[f] = *(const bf16x8*)(Asc + r * 128 + ch * 16);
        int n = wc * 64 + f * 16 + (lane & 15);
        int cb = (s * 4 + (lane >> 4)) ^ (n & 7);
        bfr[f] = *(const bf16x8*)(Bsc + n * 128 + cb * 16);
      }
#pragma unroll
      for (int fm = 0; fm < 4; ++fm)
#pragma unroll
        for (int fn = 0; fn < 4; ++fn)
          acc[fm][fn] = __builtin_amdgcn_mfma_f32_16x16x32_bf16(af[fm], bfr[fn], acc[fm][fn], 0, 0, 0);
    }
    __syncthreads();
  }
  int rbase = bm + wr * 64 + (lane >> 4) * 4;
  int cbase = bn + wc * 64 + (lane & 15);
#pragma unroll
  for (int fm = 0; fm < 4; ++fm)
#pragma unroll
    for (int fn = 0; fn < 4; ++fn) {
      int col = cbase + fn * 16;
      float bv = bias[col];
#pragma unroll
      for (int j = 0; j < 4; ++j) {
        int row = rbase + fm * 16 + j;
        float v = acc[fm][fn][j] + bv;
        if (OUT == 2) v = fmaxf(v, 0.f);
        if (OUT == 0) ((__hip_bfloat16*)Cout)[(size_t)row * N + col] = __float2bfloat16(v);
        else          ((float*)Cout)[(size_t)row * N + col] = v;
      }
    }
}

// ---------------- fused GATv2 conv1: scores+softmax+agg (online), C=64 ----------------
// one block per node; wave w = head w; lane = channel within head

__global__ __launch_bounds__(256) void gat_fused1(
    const __hip_bfloat16* __restrict__ XLR,  // [n][512]: xl|xr
    const int* __restrict__ off, const int* __restrict__ srcn,
    const float* __restrict__ eav, const float* __restrict__ We,
    const float* __restrict__ att, const float* __restrict__ bias,
    __hip_bfloat16* __restrict__ X1) {
  int d = blockIdx.x;
  int j = threadIdx.x;                     // channel in [0,256); wave = head
  const unsigned short* X = (const unsigned short*)XLR;
  float xr = bfbits2f(X[(size_t)d * 512 + 256 + j]);
  float we = We[j], at = att[j], bv = bias[j];
  int b = off[d], e1 = off[d + 1];
  float m = -INFINITY, ss = 0.f, acc = 0.f;
  for (int p = b; p < e1; ++p) {
    int s = srcn[p];
    float ea = eav[p];
    float v = bfbits2f(X[(size_t)s * 512 + j]);
    float g = v + xr + ea * we;
    g = (g > 0.f) ? g : 0.2f * g;
    float t = g * at;
#pragma unroll
    for (int o = 32; o; o >>= 1) t += __shfl_xor(t, o, 64);
    float mn = fmaxf(m, t);
    float scl = __expf(m - mn);
    float wp = __expf(t - mn);
    ss = ss * scl + wp;
    acc = acc * scl + wp * v;
    m = mn;
  }
  float outv = acc / (ss + 1e-16f) + bv;
  X1[(size_t)d * 256 + j] = __float2bfloat16(fmaxf(outv, 0.f));
}

// ---------------- fused GATv2 conv2: C=256, mean over heads ----------------
// wave w = head w; lane covers 4 channels

__global__ __launch_bounds__(256) void gat_fused2(
    const __hip_bfloat16* __restrict__ XLR,  // [n][2048]: xl(1024)|xr(1024)
    const int* __restrict__ off, const int* __restrict__ srcn,
    const float* __restrict__ eav, const float* __restrict__ We,
    const float* __restrict__ att, const float* __restrict__ bias,
    __hip_bfloat16* __restrict__ X2) {
  __shared__ float hacc[4][256];
  int d = blockIdx.x;
  int w = threadIdx.x >> 6, lane = threadIdx.x & 63;
  int cb = w * 256 + lane * 4;             // channel base in [0,1024)
  const unsigned short* X = (const unsigned short*)XLR;
  ushort4 xrv = *(const ushort4*)(X + (size_t)d * 2048 + 1024 + cb);
  float xr0 = bfbits2f(xrv.x), xr1 = bfbits2f(xrv.y), xr2 = bfbits2f(xrv.z), xr3 = bfbits2f(xrv.w);
  float we0 = We[cb], we1 = We[cb + 1], we2 = We[cb + 2], we3 = We[cb + 3];
  float at0 = att[cb], at1 = att[cb + 1], at2 = att[cb + 2], at3 = att[cb + 3];
  int b = off[d], e1 = off[d + 1];
  float m = -INFINITY, ss = 0.f;
  float a0 = 0.f, a1 = 0.f, a2 = 0.f, a3 = 0.f;
  for (int p = b; p < e1; ++p) {
    int s = srcn[p];
    float ea = eav[p];
    ushort4 vv = *(const ushort4*)(X + (size_t)s * 2048 + cb);
    float v0 = bfbits2f(vv.x), v1 = bfbits2f(vv.y), v2 = bfbits2f(vv.z), v3 = bfbits2f(vv.w);
    float g, t;
    g = v0 + xr0 + ea * we0; g = (g > 0.f) ? g : 0.2f * g; t  = g * at0;
    g = v1 + xr1 + ea * we1; g = (g > 0.f) ? g : 0.2f * g; t += g * at1;
    g = v2 + xr2 + ea * we2; g = (g > 0.f) ? g : 0.2f * g; t += g * at2;
    g = v3 + xr3 + ea * we3; g = (g > 0.f) ? g : 0.2f * g; t += g * at3;
#pragma unroll
    for (int o = 32; o; o >>= 1) t += __shfl_xor(t, o, 64);
    float mn = fmaxf(m, t);
    float scl = __expf(m - mn);
    float wp = __expf(t - mn);
    ss = ss * scl + wp;
    a0 = a0 * scl + wp * v0;
    a1 = a1 * scl + wp * v1;
    a2 = a2 * scl + wp * v2;
    a3 = a3 * scl + wp * v3;
    m = mn;
  }
  float inv = 1.f / (ss + 1e-16f);
  hacc[w][lane * 4 + 0] = a0 * inv;
  hacc[w][lane * 4 + 1] = a1 * inv;
  hacc[w][lane * 4 + 2] = a2 * inv;
  hacc[w][lane * 4 + 3] = a3 * inv;
  __syncthreads();
  int c = threadIdx.x;
  float ov = 0.25f * (hacc[0][c] + hacc[1][c] + hacc[2][c] + hacc[3][c]) + bias[c];
  X2[(size_t)d * 256 + c] = __float2bfloat16(ov);
}

// ---------------- GRU elementwise ----------------

__global__ void gru_kernel(const float* __restrict__ gi, const float* __restrict__ gh,
                           const float* __restrict__ hf, float* __restrict__ hn,
                           __hip_bfloat16* __restrict__ hnb) {
  int i = blockIdx.x;
  int c = threadIdx.x;
  size_t b = (size_t)i * 768;
  float ir = gi[b + c], iz = gi[b + 256 + c], in_ = gi[b + 512 + c];
  float hr = gh[b + c], hz = gh[b + 256 + c], hn_ = gh[b + 512 + c];
  float r = 1.f / (1.f + __expf(-(ir + hr)));
  float z = 1.f / (1.f + __expf(-(iz + hz)));
  float ng = tanhf(in_ + r * hn_);
  float h0 = hf[(size_t)i * 256 + c];
  float v = (1.f - z) * ng + z * h0;
  hn[(size_t)i * 256 + c] = v;
  hnb[(size_t)i * 256 + c] = __float2bfloat16(v);
}

// ---------------- small final head GEMM (N<=2) ----------------

template <int ACT>  // 0 none, 1 sigmoid, 2 softplus
__global__ void head_small(const float* __restrict__ T, int ld, int coloff,
                           const float* __restrict__ W, const float* __restrict__ b,
                           float* __restrict__ out, int K, int N) {
  int wid = (blockIdx.x * blockDim.x + threadIdx.x) >> 6;
  int lane = threadIdx.x & 63;
  if (wid >= N_NODES) return;
  for (int o = 0; o < N; ++o) {
    float acc = 0.f;
    for (int k = lane; k < K; k += 64) acc += T[(size_t)wid * ld + coloff + k] * W[k * N + o];
#pragma unroll
    for (int off = 32; off; off >>= 1) acc += __shfl_xor(acc, off, 64);
    if (lane == 0) {
      float v = acc + b[o];
      if (ACT == 1) v = 1.f / (1.f + __expf(-v));
      else if (ACT == 2) v = fmaxf(v, 0.f) + log1pf(__expf(-fabsf(v)));
      out[(size_t)wid * N + o] = v;
    }
  }
}

__global__ void ap_reduce(const float* __restrict__ ap, float* __restrict__ out) {
  __shared__ float sm[256];
  int b = blockIdx.x, tid = threadIdx.x;
  float acc = 0.f;
  for (int i = tid; i < 2048; i += 256) acc += ap[b * 2048 + i];
  sm[tid] = acc; __syncthreads();
  for (int s = 128; s; s >>= 1) { if (tid < s) sm[tid] += sm[tid + s]; __syncthreads(); }
  if (tid == 0) out[b] = sm[0] * (1.f / 2048.f);
}

// ---------------- launch ----------------

extern "C" void kernel_launch(void* const* d_in, const int* in_sizes, int n_in,
                              void* d_out, int out_size, void* d_ws, size_t ws_size,
                              hipStream_t stream) {
  const float* h        = (const float*)d_in[0];
  const float* c_temp   = (const float*)d_in[1];
  const float* c_stereo = (const float*)d_in[2];
  const float* e_proj   = (const float*)d_in[3];
  const float* f_Lt     = (const float*)d_in[4];
  const int*   edges    = (const int*)d_in[5];
  const float* eattr    = (const float*)d_in[6];
  const float* Wl1 = (const float*)d_in[7];  const float* bl1 = (const float*)d_in[8];
  const float* Wr1 = (const float*)d_in[9];  const float* br1 = (const float*)d_in[10];
  const float* We1 = (const float*)d_in[11]; const float* att1 = (const float*)d_in[12];
  const float* bias1 = (const float*)d_in[13];
  const float* Wl2 = (const float*)d_in[14]; const float* bl2 = (const float*)d_in[15];
  const float* Wr2 = (const float*)d_in[16]; const float* br2 = (const float*)d_in[17];
  const float* We2 = (const float*)d_in[18]; const float* att2 = (const float*)d_in[19];
  const float* bias2 = (const float*)d_in[20];
  const float* Wih = (const float*)d_in[21]; const float* bih = (const float*)d_in[22];
  const float* Whh = (const float*)d_in[23]; const float* bhh = (const float*)d_in[24];
  const float* rW1 = (const float*)d_in[25]; const float* rb1 = (const float*)d_in[26];
  const float* rW2 = (const float*)d_in[27]; const float* rb2 = (const float*)d_in[28];
  const float* wW1 = (const float*)d_in[29]; const float* wb1 = (const float*)d_in[30];
  const float* wW2 = (const float*)d_in[31]; const float* wb2 = (const float*)d_in[32];
  const float* pW1 = (const float*)d_in[33]; const float* pb1 = (const float*)d_in[34];
  const float* pW2 = (const float*)d_in[35]; const float* pb2 = (const float*)d_in[36];
  const float* dW1 = (const float*)d_in[37]; const float* db1 = (const float*)d_in[38];
  const float* dW2 = (const float*)d_in[39]; const float* db2 = (const float*)d_in[40];

  const int* src = edges;
  const int* dst = edges + E_RAW;

  // ---- workspace layout (float units, regions 64-aligned) ----
  float* base = (float*)d_ws;
  size_t cur = 0;
  auto alloc = [&](size_t n) { float* p = base + cur; cur += (n + 63) & ~(size_t)63; return p; };

  float* BIG0 = alloc(8388608);   // XLR2 (bf16 16.8M) -> gi (f32) -> T (f32)
  float* BIG1 = alloc(6291456);   // x_bf (bf16 6.8M) -> gh (f32)
  float* XLR1f = alloc(2097152);  // [8192][512] bf16
  float* X1f  = alloc(1048576);   // bf16
  float* X2f  = alloc(1048576);   // bf16
  float* Hbf  = alloc(1048576);   // bf16
  float* HNbf = alloc(1048576);   // bf16
  float* WT1f = alloc(212992);    // [512][832] bf16
  float* WT2f = alloc(262144);    // [2048][256] bf16
  float* WTihf = alloc(98304);    // [768][256] bf16
  float* WThhf = alloc(98304);
  float* WThf  = alloc(98304);
  float* B1 = alloc(512);
  float* B2 = alloc(2048);
  float* BH = alloc(768);
  float* EAV = alloc(E_TOT);
  float* AP  = alloc(N_NODES);
  float* MP  = alloc(320);
  int* ICNT = (int*)alloc(N_NODES);
  int* IPOS = (int*)alloc(N_NODES);
  int* IOFF = (int*)alloc(N_NODES + 64);
  int* ISRC = (int*)alloc(E_TOT);
  if (ws_size < cur * 4) return;

  __hip_bfloat16* x_bf = (__hip_bfloat16*)BIG1;
  __hip_bfloat16* XLR1 = (__hip_bfloat16*)XLR1f;
  __hip_bfloat16* XLR2 = (__hip_bfloat16*)BIG0;
  __hip_bfloat16* X1b = (__hip_bfloat16*)X1f;
  __hip_bfloat16* X2b = (__hip_bfloat16*)X2f;
  __hip_bfloat16* Hb  = (__hip_bfloat16*)Hbf;
  __hip_bfloat16* HNb = (__hip_bfloat16*)HNbf;
  __hip_bfloat16* WT1 = (__hip_bfloat16*)WT1f;
  __hip_bfloat16* WT2 = (__hip_bfloat16*)WT2f;
  __hip_bfloat16* WTih = (__hip_bfloat16*)WTihf;
  __hip_bfloat16* WThh = (__hip_bfloat16*)WThhf;
  __hip_bfloat16* WTh  = (__hip_bfloat16*)WThf;
  float* gi = BIG0;
  float* gh = BIG1;
  float* T  = BIG0;

  float* o_hnew = (float*)d_out;
  float* o_res  = o_hnew + (size_t)N_NODES * 256;
  float* o_w    = o_res + (size_t)N_NODES * 2;
  float* o_ap   = o_w + (size_t)N_NODES * 2;
  float* o_ad   = o_ap + 4;

  // ---- stage 0: x, ea mean, CSR, weight conversion ----
  build_x_bf<<<N_NODES, 256, 0, stream>>>(c_temp, c_stereo, e_proj, f_Lt, x_bf);
  ea_partial<<<256, 256, 0, stream>>>(eattr, MP);
  ea_final<<<1, 256, 0, stream>>>(MP, MP + 256);
  const float* eamean = MP + 256;

  fill_i<<<(2 * N_NODES + 255) / 256, 256, 0, stream>>>(ICNT, 0, 2 * N_NODES);  // ICNT+IPOS adjacent
  csr_count<<<(E_TOT + 255) / 256, 256, 0, stream>>>(dst, ICNT);
  csr_scan<<<1, 1024, 0, stream>>>(ICNT, IOFF);
  csr_fill<<<(E_TOT + 255) / 256, 256, 0, stream>>>(src, dst, eattr, eamean, IOFF, IPOS, ISRC, EAV);

  wt_conv<<<dim3(26, 8), 256, 0, stream>>>(Wl1, WT1, 770, 256, 832, 0);
  wt_conv<<<dim3(26, 8), 256, 0, stream>>>(Wr1, WT1, 770, 256, 832, 256);
  wt_conv<<<dim3(8, 32), 256, 0, stream>>>(Wl2, WT2, 256, 1024, 256, 0);
  wt_conv<<<dim3(8, 32), 256, 0, stream>>>(Wr2, WT2, 256, 1024, 256, 1024);
  wt_conv<<<dim3(8, 24), 256, 0, stream>>>(Wih, WTih, 256, 768, 256, 0);
  wt_conv<<<dim3(8, 24), 256, 0, stream>>>(Whh, WThh, 256, 768, 256, 0);
  wt_conv<<<dim3(8, 8), 256, 0, stream>>>(rW1, WTh, 256, 256, 256, 0);
  wt_conv<<<dim3(8, 8), 256, 0, stream>>>(wW1, WTh, 256, 256, 256, 256);
  wt_conv<<<dim3(8, 4), 256, 0, stream>>>(pW1, WTh, 256, 128, 256, 512);
  wt_conv<<<dim3(8, 4), 256, 0, stream>>>(dW1, WTh, 256, 128, 256, 640);
  build_biases<<<13, 256, 0, stream>>>(bl1, br1, bl2, br2, rb1, wb1, pb1, db1, B1, B2, BH);
  cvt_bf<<<(N_NODES * 256 + 255) / 256, 256, 0, stream>>>(h, Hb, N_NODES * 256);

  // ---- conv1 ----
  mfma_gemm<0><<<dim3(4, 64, 1), 256, 0, stream>>>(x_bf, WT1, B1, XLR1, 832, 512,
                                                   nullptr, nullptr, nullptr, nullptr);
  gat_fused1<<<N_NODES, 256, 0, stream>>>(XLR1, IOFF, ISRC, EAV, We1, att1, bias1, X1b);

  // ---- conv2 ----
  mfma_gemm<0><<<dim3(16, 64, 1), 256, 0, stream>>>(X1b, WT2, B2, XLR2, 256, 2048,
                                                    nullptr, nullptr, nullptr, nullptr);
  gat_fused2<<<N_NODES, 256, 0, stream>>>(XLR2, IOFF, ISRC, EAV, We2, att2, bias2, X2b);

  // ---- GRU: gi = X2@Wih+bih (z=0), gh = h@Whh+bhh (z=1) ----
  mfma_gemm<1><<<dim3(6, 64, 2), 256, 0, stream>>>(X2b, WTih, bih, gi, 256, 768,
                                                   Hb, WThh, bhh, gh);
  gru_kernel<<<N_NODES, 256, 0, stream>>>(gi, gh, h, o_hnew, HNb);

  // ---- heads: T = relu(hnew @ [rW1|wW1|pW1|dW1] + BH) ----
  mfma_gemm<2><<<dim3(6, 64, 1), 256, 0, stream>>>(HNb, WTh, BH, T, 256, 768,
                                                   nullptr, nullptr, nullptr, nullptr);
  head_small<0><<<N_NODES / 4, 256, 0, stream>>>(T, 768, 0, rW2, rb2, o_res, 256, 2);
  head_small<1><<<N_NODES / 4, 256, 0, stream>>>(T, 768, 256, wW2, wb2, o_w, 256, 2);
  head_small<2><<<N_NODES / 4, 256, 0, stream>>>(T, 768, 512, pW2, pb2, AP, 128, 1);
  ap_reduce<<<4, 256, 0, stream>>>(AP, o_ap);
  head_small<2><<<N_NODES / 4, 256, 0, stream>>>(T, 768, 640, dW2, db2, o_ad, 128, 1);
}

// Round 4
// 216.391 us; speedup vs baseline: 8.1961x; 1.4206x over previous
//
#include <hip/hip_runtime.h>
#include <hip/hip_bf16.h>
#include <cstdint>
#include <cstddef>

#define N_NODES 8192
#define E_RAW   131072
#define E_TOT   (E_RAW + N_NODES)   // 139264
#define HEADS   4

typedef __attribute__((ext_vector_type(8))) __bf16 bf16x8;
typedef __attribute__((ext_vector_type(4))) float f32x4;

__device__ __forceinline__ void gload_lds16(const void* g, void* lds) {
  __builtin_amdgcn_global_load_lds(
      (const __attribute__((address_space(1))) unsigned int*)g,
      (__attribute__((address_space(3))) unsigned int*)lds, 16, 0, 0);
}

__device__ __forceinline__ float bfbits2f(unsigned short u) {
  return __uint_as_float((unsigned)u << 16);
}
__device__ __forceinline__ unsigned short f2bfbits(float f) {
  __hip_bfloat16 b = __float2bfloat16(f);
  return *(unsigned short*)&b;
}
// one uint holds 2 bf16: lo needs shift, hi just a mask
__device__ __forceinline__ void unpk(unsigned u, float& lo, float& hi) {
  lo = __uint_as_float(u << 16);
  hi = __uint_as_float(u & 0xffff0000u);
}

__device__ __forceinline__ int eSrc(const int* __restrict__ src, int e) {
  return (e < E_RAW) ? src[e] : (e - E_RAW);
}
__device__ __forceinline__ int eDst(const int* __restrict__ dst, int e) {
  return (e < E_RAW) ? dst[e] : (e - E_RAW);
}

// ---------------- fused prep: build_x | cvt h | ea partials | fills | biases ----------------
// grid sections: [0,8192) build_x; [8192,9216) cvt h; [9216,9472) ea_partial;
// [9472,9536) fill icnt/ipos; [9536,9549) biases

__global__ __launch_bounds__(256) void prep_kernel(
    const float* __restrict__ ct, const float* __restrict__ cs,
    const float* __restrict__ ep, const float* __restrict__ fl,
    const float* __restrict__ h, const float* __restrict__ ea,
    const float* bl1, const float* br1, const float* bl2, const float* br2,
    const float* rb1, const float* wb1, const float* pb1, const float* db1,
    __hip_bfloat16* __restrict__ x, __hip_bfloat16* __restrict__ Hb,
    float* __restrict__ MP, int* __restrict__ icnt_ipos,
    float* B1, float* B2, float* BH) {
  int blk = blockIdx.x;
  int tid = threadIdx.x;
  if (blk < 8192) {
    int i = blk;
    for (int j = tid; j < 832; j += 256) {
      float v;
      if (j < 256)      v = ct[(size_t)i * 256 + j];
      else if (j < 512) v = cs[(size_t)i * 256 + (j - 256)];
      else if (j < 514) v = ep[(size_t)i * 2 + (j - 512)];
      else if (j < 770) v = fl[(size_t)i * 256 + (j - 514)];
      else              v = 0.f;
      x[(size_t)i * 832 + j] = __float2bfloat16(v);
    }
  } else if (blk < 9216) {
    size_t base = ((size_t)(blk - 8192) * 256 + tid) * 8;
    float4 a = *(const float4*)(h + base);
    float4 b = *(const float4*)(h + base + 4);
    unsigned short o[8];
    o[0]=f2bfbits(a.x); o[1]=f2bfbits(a.y); o[2]=f2bfbits(a.z); o[3]=f2bfbits(a.w);
    o[4]=f2bfbits(b.x); o[5]=f2bfbits(b.y); o[6]=f2bfbits(b.z); o[7]=f2bfbits(b.w);
    *(uint4*)((unsigned short*)Hb + base) = *(uint4*)o;
  } else if (blk < 9472) {
    __shared__ float sm[256];
    int bb = blk - 9216;
    float acc = 0.f;
    for (int i = bb * 256 + tid; i < E_RAW; i += 256 * 256) acc += ea[i];
    sm[tid] = acc; __syncthreads();
    for (int s = 128; s; s >>= 1) { if (tid < s) sm[tid] += sm[tid + s]; __syncthreads(); }
    if (tid == 0) MP[bb] = sm[0];
  } else if (blk < 9536) {
    int i = (blk - 9472) * 256 + tid;
    if (i < 2 * N_NODES) icnt_ipos[i] = 0;
  } else {
    int i = (blk - 9536) * 256 + tid;
    if (i < 512) B1[i] = (i < 256) ? bl1[i] : br1[i - 256];
    else if (i < 2560) { int k = i - 512; B2[k] = (k < 1024) ? bl2[k] : br2[k - 1024]; }
    else if (i < 3328) {
      int k = i - 2560;
      BH[k] = (k < 256) ? rb1[k] : (k < 512) ? wb1[k - 256] : (k < 640) ? pb1[k - 512] : db1[k - 640];
    }
  }
}

// ---------------- CSR build ----------------

__global__ void csr_count(const int* __restrict__ dst, int* __restrict__ cnt) {
  int e = blockIdx.x * blockDim.x + threadIdx.x;
  if (e < E_TOT) atomicAdd(&cnt[eDst(dst, e)], 1);
}

// scan of 8192 + ea mean finalize
__global__ __launch_bounds__(1024) void csr_scan(const int* __restrict__ cnt,
                                                 int* __restrict__ off,
                                                 float* __restrict__ MP) {
  __shared__ int part[1024];
  __shared__ float sm[256];
  int t = threadIdx.x;
  if (t < 256) sm[t] = MP[t];
  __syncthreads();
  for (int s = 128; s; s >>= 1) { if (t < s) sm[t] += sm[t + s]; __syncthreads(); }
  if (t == 0) MP[256] = sm[0] * (1.f / (float)E_RAW);
  int base = t * 8;
  int loc[8];
  int s = 0;
#pragma unroll
  for (int i = 0; i < 8; ++i) { loc[i] = s; s += cnt[base + i]; }
  part[t] = s; __syncthreads();
  for (int d = 1; d < 1024; d <<= 1) {
    int v = (t >= d) ? part[t - d] : 0;
    __syncthreads();
    part[t] += v;
    __syncthreads();
  }
  int pre = (t == 0) ? 0 : part[t - 1];
#pragma unroll
  for (int i = 0; i < 8; ++i) off[base + i] = pre + loc[i];
  if (t == 1023) off[8192] = part[1023];
}

__global__ void csr_fill(const int* __restrict__ src, const int* __restrict__ dst,
                         const float* __restrict__ ea, const float* __restrict__ eamean,
                         const int* __restrict__ off, int* __restrict__ pos,
                         int* __restrict__ srcn, float* __restrict__ eav) {
  int e = blockIdx.x * blockDim.x + threadIdx.x;
  if (e >= E_TOT) return;
  int d = eDst(dst, e);
  int p = off[d] + atomicAdd(&pos[d], 1);
  srcn[p] = eSrc(src, e);
  eav[p] = (e < E_RAW) ? ea[e] : eamean[0];
}

// ---------------- all weight transposes in one launch ----------------
// jobs: Wl1,Wr1 -> WT1[512][832]; Wl2,Wr2 -> WT2[2048][256];
// Wih -> WTih; Whh -> WThh; rW1,wW1,pW1,dW1 -> WTh[768][256]

__global__ __launch_bounds__(256) void wt_all(
    const float* w0, const float* w1, const float* w2, const float* w3,
    const float* w4, const float* w5, const float* w6, const float* w7,
    const float* w8, const float* w9,
    __hip_bfloat16* WT1, __hip_bfloat16* WT2, __hip_bfloat16* WTih,
    __hip_bfloat16* WThh, __hip_bfloat16* WTh) {
  const int cum[10] = {208, 416, 672, 928, 1120, 1312, 1376, 1440, 1472, 1504};
  const int Kt[10]  = {770, 770, 256, 256, 256, 256, 256, 256, 256, 256};
  const int Nt[10]  = {256, 256, 1024, 1024, 768, 768, 256, 256, 128, 128};
  const int KPt[10] = {832, 832, 256, 256, 256, 256, 256, 256, 256, 256};
  const int n0t[10] = {0, 256, 0, 1024, 0, 0, 0, 256, 512, 640};
  int job = 0;
  while (blockIdx.x >= (unsigned)cum[job]) ++job;
  int lb = blockIdx.x - (job ? cum[job - 1] : 0);
  int K = Kt[job], N = Nt[job], KP = KPt[job], n0 = n0t[job];
  int tilesX = KP >> 5;
  int k0 = (lb % tilesX) * 32, nb = (lb / tilesX) * 32;
  const float* W;
  switch (job) {
    case 0: W = w0; break; case 1: W = w1; break; case 2: W = w2; break;
    case 3: W = w3; break; case 4: W = w4; break; case 5: W = w5; break;
    case 6: W = w6; break; case 7: W = w7; break; case 8: W = w8; break;
    default: W = w9; break;
  }
  __hip_bfloat16* WT = (job < 2) ? WT1 : (job < 4) ? WT2 : (job == 4) ? WTih
                       : (job == 5) ? WThh : WTh;
  __shared__ float sm[32][33];
  int tx = threadIdx.x & 31, ty = threadIdx.x >> 5;
  for (int yy = ty; yy < 32; yy += 8) {
    int k = k0 + yy, n = nb + tx;
    sm[yy][tx] = (k < K && n < N) ? W[(size_t)k * N + n] : 0.f;
  }
  __syncthreads();
  for (int yy = ty; yy < 32; yy += 8) {
    int n = nb + yy, k = k0 + tx;
    if (n < N) WT[(size_t)(n0 + n) * KP + k] = __float2bfloat16(sm[tx][yy]);
  }
}

// ---------------- bf16 MFMA GEMM (128x128 tile, BK=64, swizzled LDS) ----------------

template <int OUT>  // 0: bf16 store, 1: f32 store, 2: f32 relu store
__global__ __launch_bounds__(256) void mfma_gemm(
    const __hip_bfloat16* __restrict__ A, const __hip_bfloat16* __restrict__ BT,
    const float* __restrict__ bias, void* __restrict__ Cout, int KP, int N,
    const __hip_bfloat16* A2, const __hip_bfloat16* BT2,
    const float* bias2, void* C2) {
  if (blockIdx.z == 1) { A = A2; BT = BT2; bias = bias2; Cout = C2; }
  __shared__ uint4 AsBuf[1024];
  __shared__ uint4 BsBuf[1024];
  char* Asc = (char*)AsBuf;
  char* Bsc = (char*)BsBuf;
  int tid = threadIdx.x;
  int lane = tid & 63;
  int wid = tid >> 6;
  int wr = wid >> 1, wc = wid & 1;
  int bm = blockIdx.y * 128;
  int bn = blockIdx.x * 128;
  f32x4 acc[4][4];
#pragma unroll
  for (int i = 0; i < 4; ++i)
#pragma unroll
    for (int j = 0; j < 4; ++j) acc[i][j] = (f32x4){0.f, 0.f, 0.f, 0.f};

  int nK = KP >> 6;
  for (int kt = 0; kt < nK; ++kt) {
    int k0 = kt * 64;
#pragma unroll
    for (int i = 0; i < 4; ++i) {
      int p = i * 256 + tid;
      int row = p >> 3, cc = p & 7;
      int sc = cc ^ (row & 7);
      gload_lds16(A + (size_t)(bm + row) * KP + k0 + sc * 8, Asc + p * 16);
      gload_lds16(BT + (size_t)(bn + row) * KP + k0 + sc * 8, Bsc + p * 16);
    }
    __syncthreads();
#pragma unroll
    for (int s = 0; s < 2; ++s) {
      bf16x8 af[4], bfr[4];
#pragma unroll
      for (int f = 0; f < 4; ++f) {
        int r = wr * 64 + f * 16 + (lane & 15);
        int ch = (s * 4 + (lane >> 4)) ^ (r & 7);
        af[f] = *(const bf16x8*)(Asc + r * 128 + ch * 16);
        int n = wc * 64 + f * 16 + (lane & 15);
        int cb = (s * 4 + (lane >> 4)) ^ (n & 7);
        bfr[f] = *(const bf16x8*)(Bsc + n * 128 + cb * 16);
      }
#pragma unroll
      for (int fm = 0; fm < 4; ++fm)
#pragma unroll
        for (int fn = 0; fn < 4; ++fn)
          acc[fm][fn] = __builtin_amdgcn_mfma_f32_16x16x32_bf16(af[fm], bfr[fn], acc[fm][fn], 0, 0, 0);
    }
    __syncthreads();
  }
  int rbase = bm + wr * 64 + (lane >> 4) * 4;
  int cbase = bn + wc * 64 + (lane & 15);
#pragma unroll
  for (int fm = 0; fm < 4; ++fm)
#pragma unroll
    for (int fn = 0; fn < 4; ++fn) {
      int col = cbase + fn * 16;
      float bv = bias[col];
#pragma unroll
      for (int j = 0; j < 4; ++j) {
        int row = rbase + fm * 16 + j;
        float v = acc[fm][fn][j] + bv;
        if (OUT == 2) v = fmaxf(v, 0.f);
        if (OUT == 0) ((__hip_bfloat16*)Cout)[(size_t)row * N + col] = __float2bfloat16(v);
        else          ((float*)Cout)[(size_t)row * N + col] = v;
      }
    }
}

// ---------------- fused GATv2 conv1: ONE wave per node, 4 ch/lane ----------------
// lane: head g=lane>>4, q=lane&15, channels j0=g*64+q*4 .. +3
// score reduce: 4-stage xor within 16-lane head group; exact defer-max online softmax

__global__ __launch_bounds__(256) void gat_fused1(
    const __hip_bfloat16* __restrict__ XLR,  // [n][512] xl|xr
    const int* __restrict__ off, const int* __restrict__ srcn,
    const float* __restrict__ eav, const float* __restrict__ We,
    const float* __restrict__ att, const float* __restrict__ bias,
    __hip_bfloat16* __restrict__ X1) {
  int d = (blockIdx.x * 256 + threadIdx.x) >> 6;
  int lane = threadIdx.x & 63;
  int g = lane >> 4, q = lane & 15;
  int j0 = g * 64 + q * 4;
  const unsigned short* X = (const unsigned short*)XLR;
  ushort4 xrv = *(const ushort4*)(X + (size_t)d * 512 + 256 + j0);
  float xr[4] = {bfbits2f(xrv.x), bfbits2f(xrv.y), bfbits2f(xrv.z), bfbits2f(xrv.w)};
  float4 wev = *(const float4*)(We + j0);
  float4 atv = *(const float4*)(att + j0);
  float we[4] = {wev.x, wev.y, wev.z, wev.w};
  float at[4] = {atv.x, atv.y, atv.z, atv.w};
  int b = off[d], e1 = off[d + 1];
  int pe = e1 - 1;
  // 2-deep prefetch: row for edge p, ids for edge p+1
  int sB = srcn[b]; float eaA = eav[b];
  ushort4 vvA = *(const ushort4*)(X + (size_t)sB * 512 + j0);
  int p1 = (b + 1 <= pe) ? b + 1 : pe;
  sB = srcn[p1]; float eaB = eav[p1];
  float m = -INFINITY, ss = 0.f;
  float a[4] = {0.f, 0.f, 0.f, 0.f};
  for (int p = b; p < e1; ++p) {
    ushort4 vv = vvA; float ea = eaA;
    eaA = eaB;
    vvA = *(const ushort4*)(X + (size_t)sB * 512 + j0);  // row p+1
    int p2 = (p + 2 <= pe) ? p + 2 : pe;
    sB = srcn[p2]; eaB = eav[p2];
    float v[4] = {bfbits2f(vv.x), bfbits2f(vv.y), bfbits2f(vv.z), bfbits2f(vv.w)};
    float t = 0.f;
#pragma unroll
    for (int i = 0; i < 4; ++i) {
      float gg = fmaf(ea, we[i], v[i] + xr[i]);
      float lr = fmaxf(gg, 0.2f * gg);
      t = fmaf(lr, at[i], t);
    }
    t += __shfl_xor(t, 8, 64); t += __shfl_xor(t, 4, 64);
    t += __shfl_xor(t, 2, 64); t += __shfl_xor(t, 1, 64);
    if (__all(t <= m)) {
      float wp = __expf(t - m);
      ss += wp;
#pragma unroll
      for (int i = 0; i < 4; ++i) a[i] = fmaf(wp, v[i], a[i]);
    } else {
      float mn = fmaxf(m, t);
      float scl = __expf(m - mn);
      float wp = __expf(t - mn);
      ss = fmaf(ss, scl, wp);
#pragma unroll
      for (int i = 0; i < 4; ++i) a[i] = fmaf(wp, v[i], a[i] * scl);
      m = mn;
    }
  }
  float inv = 1.f / (ss + 1e-16f);
  unsigned short o[4];
#pragma unroll
  for (int i = 0; i < 4; ++i)
    o[i] = f2bfbits(fmaxf(fmaf(a[i], inv, bias[j0 + i]), 0.f));
  *(ushort4*)((unsigned short*)X1 + (size_t)d * 256 + j0) = *(ushort4*)o;
}

// ---------------- fused GATv2 conv2: ONE wave per node, 16 ch/lane, head-mean ----------------
// lane: head g=lane>>4, q=lane&15, channels j0=g*256+q*16 .. +15

__global__ __launch_bounds__(256) void gat_fused2(
    const __hip_bfloat16* __restrict__ XLR,  // [n][2048] xl|xr
    const int* __restrict__ off, const int* __restrict__ srcn,
    const float* __restrict__ eav, const float* __restrict__ We,
    const float* __restrict__ att, const float* __restrict__ bias,
    __hip_bfloat16* __restrict__ X2) {
  int d = (blockIdx.x * 256 + threadIdx.x) >> 6;
  int lane = threadIdx.x & 63;
  int g = lane >> 4, q = lane & 15;
  int j0 = g * 256 + q * 16;
  const unsigned short* X = (const unsigned short*)XLR;
  float xr[16], we[16], at[16];
  {
    const uint4* xp = (const uint4*)(X + (size_t)d * 2048 + 1024 + j0);
    uint4 r0 = xp[0], r1 = xp[1];
    unpk(r0.x, xr[0], xr[1]); unpk(r0.y, xr[2], xr[3]);
    unpk(r0.z, xr[4], xr[5]); unpk(r0.w, xr[6], xr[7]);
    unpk(r1.x, xr[8], xr[9]); unpk(r1.y, xr[10], xr[11]);
    unpk(r1.z, xr[12], xr[13]); unpk(r1.w, xr[14], xr[15]);
#pragma unroll
    for (int i = 0; i < 16; i += 4) {
      float4 w4 = *(const float4*)(We + j0 + i);
      float4 a4 = *(const float4*)(att + j0 + i);
      we[i] = w4.x; we[i + 1] = w4.y; we[i + 2] = w4.z; we[i + 3] = w4.w;
      at[i] = a4.x; at[i + 1] = a4.y; at[i + 2] = a4.z; at[i + 3] = a4.w;
    }
  }
  int b = off[d], e1 = off[d + 1];
  int pe = e1 - 1;
  int sB = srcn[b]; float eaA = eav[b];
  const uint4* rp = (const uint4*)(X + (size_t)sB * 2048 + j0);
  uint4 rA0 = rp[0], rA1 = rp[1];
  int p1 = (b + 1 <= pe) ? b + 1 : pe;
  sB = srcn[p1]; float eaB = eav[p1];
  float m = -INFINITY, ss = 0.f;
  float a[16];
#pragma unroll
  for (int i = 0; i < 16; ++i) a[i] = 0.f;
  for (int p = b; p < e1; ++p) {
    uint4 c0 = rA0, c1 = rA1; float ea = eaA;
    eaA = eaB;
    rp = (const uint4*)(X + (size_t)sB * 2048 + j0);
    rA0 = rp[0]; rA1 = rp[1];
    int p2 = (p + 2 <= pe) ? p + 2 : pe;
    sB = srcn[p2]; eaB = eav[p2];
    float v[16];
    unpk(c0.x, v[0], v[1]); unpk(c0.y, v[2], v[3]);
    unpk(c0.z, v[4], v[5]); unpk(c0.w, v[6], v[7]);
    unpk(c1.x, v[8], v[9]); unpk(c1.y, v[10], v[11]);
    unpk(c1.z, v[12], v[13]); unpk(c1.w, v[14], v[15]);
    float t = 0.f;
#pragma unroll
    for (int i = 0; i < 16; ++i) {
      float gg = fmaf(ea, we[i], v[i] + xr[i]);
      float lr = fmaxf(gg, 0.2f * gg);
      t = fmaf(lr, at[i], t);
    }
    t += __shfl_xor(t, 8, 64); t += __shfl_xor(t, 4, 64);
    t += __shfl_xor(t, 2, 64); t += __shfl_xor(t, 1, 64);
    if (__all(t <= m)) {
      float wp = __expf(t - m);
      ss += wp;
#pragma unroll
      for (int i = 0; i < 16; ++i) a[i] = fmaf(wp, v[i], a[i]);
    } else {
      float mn = fmaxf(m, t);
      float scl = __expf(m - mn);
      float wp = __expf(t - mn);
      ss = fmaf(ss, scl, wp);
#pragma unroll
      for (int i = 0; i < 16; ++i) a[i] = fmaf(wp, v[i], a[i] * scl);
      m = mn;
    }
  }
  float inv = 1.f / (ss + 1e-16f);
  // mean over heads: sum across lane groups (xor 16, 32), then g==0 stores
#pragma unroll
  for (int i = 0; i < 16; ++i) {
    float r = a[i] * inv;
    r += __shfl_xor(r, 16, 64);
    r += __shfl_xor(r, 32, 64);
    a[i] = r;
  }
  if (g == 0) {
    unsigned short o[16];
#pragma unroll
    for (int i = 0; i < 16; ++i)
      o[i] = f2bfbits(fmaf(0.25f, a[i], bias[q * 16 + i]));
    uint4* op = (uint4*)((unsigned short*)X2 + (size_t)d * 256 + q * 16);
    op[0] = ((uint4*)o)[0];
    op[1] = ((uint4*)o)[1];
  }
}

// ---------------- GRU elementwise ----------------

__global__ void gru_kernel(const float* __restrict__ gi, const float* __restrict__ gh,
                           const float* __restrict__ hf, float* __restrict__ hn,
                           __hip_bfloat16* __restrict__ hnb) {
  int i = blockIdx.x;
  int c = threadIdx.x;
  size_t b = (size_t)i * 768;
  float ir = gi[b + c], iz = gi[b + 256 + c], in_ = gi[b + 512 + c];
  float hr = gh[b + c], hz = gh[b + 256 + c], hn_ = gh[b + 512 + c];
  float r = 1.f / (1.f + __expf(-(ir + hr)));
  float z = 1.f / (1.f + __expf(-(iz + hz)));
  float ng = tanhf(in_ + r * hn_);
  float h0 = hf[(size_t)i * 256 + c];
  float v = (1.f - z) * ng + z * h0;
  hn[(size_t)i * 256 + c] = v;
  hnb[(size_t)i * 256 + c] = __float2bfloat16(v);
}

// ---------------- all 4 final heads in one kernel: wave per node ----------------
// T row layout: [0,256) res-relu | [256,512) w-relu | [512,640) p-relu | [640,768) d-relu

__global__ __launch_bounds__(256) void heads_final(
    const float* __restrict__ T,
    const float* __restrict__ rW2, const float* __restrict__ rb2,
    const float* __restrict__ wW2, const float* __restrict__ wb2,
    const float* __restrict__ pW2, const float* __restrict__ pb2,
    const float* __restrict__ dW2, const float* __restrict__ db2,
    float* __restrict__ o_res, float* __restrict__ o_w,
    float* __restrict__ AP, float* __restrict__ o_ad) {
  int node = (blockIdx.x * 256 + threadIdx.x) >> 6;
  int lane = threadIdx.x & 63;
  const float* t = T + (size_t)node * 768;
  float4 tr = *(const float4*)(t + lane * 4);
  float4 tw = *(const float4*)(t + 256 + lane * 4);
  float4 tp = {0.f, 0.f, 0.f, 0.f}, td = {0.f, 0.f, 0.f, 0.f};
  if (lane < 32) {
    tp = *(const float4*)(t + 512 + lane * 4);
    td = *(const float4*)(t + 640 + lane * 4);
  }
  float r0 = 0.f, r1 = 0.f, w0 = 0.f, w1 = 0.f, pp = 0.f, dd = 0.f;
#pragma unroll
  for (int i = 0; i < 4; ++i) {
    int k = lane * 4 + i;
    float trv = (i == 0) ? tr.x : (i == 1) ? tr.y : (i == 2) ? tr.z : tr.w;
    float twv = (i == 0) ? tw.x : (i == 1) ? tw.y : (i == 2) ? tw.z : tw.w;
    r0 = fmaf(trv, rW2[k * 2], r0);
    r1 = fmaf(trv, rW2[k * 2 + 1], r1);
    w0 = fmaf(twv, wW2[k * 2], w0);
    w1 = fmaf(twv, wW2[k * 2 + 1], w1);
  }
  if (lane < 32) {
#pragma unroll
    for (int i = 0; i < 4; ++i) {
      int k = lane * 4 + i;
      float tpv = (i == 0) ? tp.x : (i == 1) ? tp.y : (i == 2) ? tp.z : tp.w;
      float tdv = (i == 0) ? td.x : (i == 1) ? td.y : (i == 2) ? td.z : td.w;
      pp = fmaf(tpv, pW2[k], pp);
      dd = fmaf(tdv, dW2[k], dd);
    }
  }
#pragma unroll
  for (int o = 32; o; o >>= 1) {
    r0 += __shfl_xor(r0, o, 64); r1 += __shfl_xor(r1, o, 64);
    w0 += __shfl_xor(w0, o, 64); w1 += __shfl_xor(w1, o, 64);
    pp += __shfl_xor(pp, o, 64); dd += __shfl_xor(dd, o, 64);
  }
  if (lane == 0) {
    o_res[(size_t)node * 2]     = r0 + rb2[0];
    o_res[(size_t)node * 2 + 1] = r1 + rb2[1];
    float sw0 = w0 + wb2[0], sw1 = w1 + wb2[1];
    o_w[(size_t)node * 2]     = 1.f / (1.f + __expf(-sw0));
    o_w[(size_t)node * 2 + 1] = 1.f / (1.f + __expf(-sw1));
    float vp = pp + pb2[0];
    AP[node] = fmaxf(vp, 0.f) + log1pf(__expf(-fabsf(vp)));
    float vd = dd + db2[0];
    o_ad[node] = fmaxf(vd, 0.f) + log1pf(__expf(-fabsf(vd)));
  }
}

__global__ void ap_reduce(const float* __restrict__ ap, float* __restrict__ out) {
  __shared__ float sm[256];
  int b = blockIdx.x, tid = threadIdx.x;
  float acc = 0.f;
  for (int i = tid; i < 2048; i += 256) acc += ap[b * 2048 + i];
  sm[tid] = acc; __syncthreads();
  for (int s = 128; s; s >>= 1) { if (tid < s) sm[tid] += sm[tid + s]; __syncthreads(); }
  if (tid == 0) out[b] = sm[0] * (1.f / 2048.f);
}

// ---------------- launch ----------------

extern "C" void kernel_launch(void* const* d_in, const int* in_sizes, int n_in,
                              void* d_out, int out_size, void* d_ws, size_t ws_size,
                              hipStream_t stream) {
  const float* h        = (const float*)d_in[0];
  const float* c_temp   = (const float*)d_in[1];
  const float* c_stereo = (const float*)d_in[2];
  const float* e_proj   = (const float*)d_in[3];
  const float* f_Lt     = (const float*)d_in[4];
  const int*   edges    = (const int*)d_in[5];
  const float* eattr    = (const float*)d_in[6];
  const float* Wl1 = (const float*)d_in[7];  const float* bl1 = (const float*)d_in[8];
  const float* Wr1 = (const float*)d_in[9];  const float* br1 = (const float*)d_in[10];
  const float* We1 = (const float*)d_in[11]; const float* att1 = (const float*)d_in[12];
  const float* bias1 = (const float*)d_in[13];
  const float* Wl2 = (const float*)d_in[14]; const float* bl2 = (const float*)d_in[15];
  const float* Wr2 = (const float*)d_in[16]; const float* br2 = (const float*)d_in[17];
  const float* We2 = (const float*)d_in[18]; const float* att2 = (const float*)d_in[19];
  const float* bias2 = (const float*)d_in[20];
  const float* Wih = (const float*)d_in[21]; const float* bih = (const float*)d_in[22];
  const float* Whh = (const float*)d_in[23]; const float* bhh = (const float*)d_in[24];
  const float* rW1 = (const float*)d_in[25]; const float* rb1 = (const float*)d_in[26];
  const float* rW2 = (const float*)d_in[27]; const float* rb2 = (const float*)d_in[28];
  const float* wW1 = (const float*)d_in[29]; const float* wb1 = (const float*)d_in[30];
  const float* wW2 = (const float*)d_in[31]; const float* wb2 = (const float*)d_in[32];
  const float* pW1 = (const float*)d_in[33]; const float* pb1 = (const float*)d_in[34];
  const float* pW2 = (const float*)d_in[35]; const float* pb2 = (const float*)d_in[36];
  const float* dW1 = (const float*)d_in[37]; const float* db1 = (const float*)d_in[38];
  const float* dW2 = (const float*)d_in[39]; const float* db2 = (const float*)d_in[40];

  const int* src = edges;
  const int* dst = edges + E_RAW;

  float* base = (float*)d_ws;
  size_t cur = 0;
  auto alloc = [&](size_t n) { float* p = base + cur; cur += (n + 63) & ~(size_t)63; return p; };

  float* BIG0 = alloc(8388608);   // XLR2 (bf16 16.8M elems) -> gi (f32) -> T (f32)
  float* BIG1 = alloc(6291456);   // x_bf (bf16) -> gh (f32)
  float* XLR1f = alloc(2097152);  // [8192][512] bf16
  float* X1f  = alloc(1048576);
  float* X2f  = alloc(1048576);
  float* Hbf  = alloc(1048576);
  float* HNbf = alloc(1048576);
  float* WT1f = alloc(212992);
  float* WT2f = alloc(262144);
  float* WTihf = alloc(98304);
  float* WThhf = alloc(98304);
  float* WThf  = alloc(98304);
  float* B1 = alloc(512);
  float* B2 = alloc(2048);
  float* BH = alloc(768);
  float* EAV = alloc(E_TOT);
  float* AP  = alloc(N_NODES);
  float* MP  = alloc(320);
  int* ICNT = (int*)alloc(2 * N_NODES);   // ICNT + IPOS adjacent
  int* IOFF = (int*)alloc(N_NODES + 64);
  int* ISRC = (int*)alloc(E_TOT);
  if (ws_size < cur * 4) return;
  int* IPOS = ICNT + N_NODES;

  __hip_bfloat16* x_bf = (__hip_bfloat16*)BIG1;
  __hip_bfloat16* XLR1 = (__hip_bfloat16*)XLR1f;
  __hip_bfloat16* XLR2 = (__hip_bfloat16*)BIG0;
  __hip_bfloat16* X1b = (__hip_bfloat16*)X1f;
  __hip_bfloat16* X2b = (__hip_bfloat16*)X2f;
  __hip_bfloat16* Hb  = (__hip_bfloat16*)Hbf;
  __hip_bfloat16* HNb = (__hip_bfloat16*)HNbf;
  __hip_bfloat16* WT1 = (__hip_bfloat16*)WT1f;
  __hip_bfloat16* WT2 = (__hip_bfloat16*)WT2f;
  __hip_bfloat16* WTih = (__hip_bfloat16*)WTihf;
  __hip_bfloat16* WThh = (__hip_bfloat16*)WThhf;
  __hip_bfloat16* WTh  = (__hip_bfloat16*)WThf;
  float* gi = BIG0;
  float* gh = BIG1;
  float* T  = BIG0;

  float* o_hnew = (float*)d_out;
  float* o_res  = o_hnew + (size_t)N_NODES * 256;
  float* o_w    = o_res + (size_t)N_NODES * 2;
  float* o_ap   = o_w + (size_t)N_NODES * 2;
  float* o_ad   = o_ap + 4;

  // ---- prep (fused) ----
  prep_kernel<<<9549, 256, 0, stream>>>(c_temp, c_stereo, e_proj, f_Lt, h, eattr,
                                        bl1, br1, bl2, br2, rb1, wb1, pb1, db1,
                                        x_bf, Hb, MP, ICNT, B1, B2, BH);
  csr_count<<<(E_TOT + 255) / 256, 256, 0, stream>>>(dst, ICNT);
  csr_scan<<<1, 1024, 0, stream>>>(ICNT, IOFF, MP);
  csr_fill<<<(E_TOT + 255) / 256, 256, 0, stream>>>(src, dst, eattr, MP + 256,
                                                    IOFF, IPOS, ISRC, EAV);
  wt_all<<<1504, 256, 0, stream>>>(Wl1, Wr1, Wl2, Wr2, Wih, Whh, rW1, wW1, pW1, dW1,
                                   WT1, WT2, WTih, WThh, WTh);

  // ---- conv1 ----
  mfma_gemm<0><<<dim3(4, 64, 1), 256, 0, stream>>>(x_bf, WT1, B1, XLR1, 832, 512,
                                                   nullptr, nullptr, nullptr, nullptr);
  gat_fused1<<<N_NODES / 4, 256, 0, stream>>>(XLR1, IOFF, ISRC, EAV, We1, att1, bias1, X1b);

  // ---- conv2 ----
  mfma_gemm<0><<<dim3(16, 64, 1), 256, 0, stream>>>(X1b, WT2, B2, XLR2, 256, 2048,
                                                    nullptr, nullptr, nullptr, nullptr);
  gat_fused2<<<N_NODES / 4, 256, 0, stream>>>(XLR2, IOFF, ISRC, EAV, We2, att2, bias2, X2b);

  // ---- GRU ----
  mfma_gemm<1><<<dim3(6, 64, 2), 256, 0, stream>>>(X2b, WTih, bih, gi, 256, 768,
                                                   Hb, WThh, bhh, gh);
  gru_kernel<<<N_NODES, 256, 0, stream>>>(gi, gh, h, o_hnew, HNb);

  // ---- heads ----
  mfma_gemm<2><<<dim3(6, 64, 1), 256, 0, stream>>>(HNb, WTh, BH, T, 256, 768,
                                                   nullptr, nullptr, nullptr, nullptr);
  heads_final<<<N_NODES / 4, 256, 0, stream>>>(T, rW2, rb2, wW2, wb2, pW2, pb2, dW2, db2,
                                               o_res, o_w, AP, o_ad);
  ap_reduce<<<4, 256, 0, stream>>>(AP, o_ap);
}